// Round 6
// baseline (78.787 us; speedup 1.0000x reference)
//
#include <hip/hip_runtime.h>
#include <stddef.h>

#define CIN  128
#define COUT 128
#define KK   27
#define CAP  256          // pair capacity per (k, 2048-row superblock); mean 49, 30 sigma

typedef short bf16x8 __attribute__((ext_vector_type(8)));
typedef float f32x4  __attribute__((ext_vector_type(4)));

__device__ __forceinline__ short f2bf(float f) {
    unsigned u = __float_as_uint(f);
    unsigned r = (u + 0x7fffu + ((u >> 16) & 1u)) >> 16;
    return (short)r;
}
__device__ __forceinline__ float bf2f(short s) {
    unsigned u = ((unsigned)(unsigned short)s) << 16;
    return __uint_as_float(u);
}

#define PACK_UNITS (KK * 4 * 8 * 64)          // 55296 B-fragment slots
#define PACKB ((PACK_UNITS + 255) / 256)      // 216 blocks

// ============================================================================
// K1 prep: blocks [0,PACKB) pack W fp32 -> bf16 MFMA B-fragment order:
//   Wp[(((k*4+ks)*8+nf)*64+lane)*8 + j] = bf16(W[k][ks*32+(lane>>4)*8+j][nf*16+(lane&15)])
// Blocks [PACKB,..): bucket compaction for (k, superblock of 2048 rows):
//   ballot-prefix (block-local only, no atomics, no cross-block scan) appends
//   (n, src) pairs n-sorted into pairs[bucket*CAP ..]; bcnt[bucket] = count.
// k==13 buckets empty (center is identity: nbr[13][n]==n by construction).
// ============================================================================
__global__ __launch_bounds__(256) void prep(
    const float* __restrict__ W, short* __restrict__ Wp,
    const int* __restrict__ nbr, int N, int nsb,
    int* __restrict__ bcnt, int2* __restrict__ pairs)
{
    if (blockIdx.x < PACKB) {
        int fl = blockIdx.x * 256 + threadIdx.x;
        if (fl >= PACK_UNITS) return;
        int lane = fl & 63, nf = (fl >> 6) & 7, ks = (fl >> 9) & 3, k = fl >> 11;
        int col  = nf * 16 + (lane & 15);
        int krow = ks * 32 + (lane >> 4) * 8;
        bf16x8 v;
        #pragma unroll
        for (int j = 0; j < 8; ++j)
            v[j] = f2bf(W[((size_t)k * CIN + krow + j) * COUT + col]);
        *reinterpret_cast<bf16x8*>(Wp + (size_t)fl * 8) = v;
        return;
    }

    int b = blockIdx.x - PACKB;                // bucket = k*nsb + sb
    int k = b / nsb, sb = b - k * nsb;
    __shared__ int wtot[4];
    __shared__ int sbase;
    if (threadIdx.x == 0) sbase = 0;
    if (k == 13) { if (threadIdx.x == 0) bcnt[b] = 0; return; }
    __syncthreads();

    const int* nk = nbr + (size_t)k * N;
    int wave = threadIdx.x >> 6, lane = threadIdx.x & 63;
    for (int c = 0; c < 8; ++c) {
        int n = sb * 2048 + c * 256 + threadIdx.x;
        int src = (n < N) ? nk[n] : -1;
        bool valid = (src >= 0);
        unsigned long long m = __ballot(valid);
        if (lane == 0) wtot[wave] = __popcll(m);
        __syncthreads();
        int off = sbase;
        for (int w = 0; w < wave; ++w) off += wtot[w];
        off += __popcll(m & ((1ull << lane) - 1ull));
        if (valid && off < CAP)
            pairs[(size_t)b * CAP + off] = make_int2(n, src);
        __syncthreads();
        if (threadIdx.x == 0) sbase += wtot[0] + wtot[1] + wtot[2] + wtot[3];
        __syncthreads();
    }
    if (threadIdx.x == 0) bcnt[b] = (sbase < CAP) ? sbase : CAP;
}

// ============================================================================
// K2 sparse GEMM: one block per bucket. Direct-gather MFMA (no LDS):
// each lane loads its 32B fp32 A-slice from feats, converts in-register.
// Results -> bf16 partial rows indexed by bucket slot (collision-free).
// ============================================================================
__global__ __launch_bounds__(256) void sparse_gemm(
    const float* __restrict__ feats, const short* __restrict__ Wp,
    const int2* __restrict__ pairs, const int* __restrict__ bcnt,
    short* __restrict__ partial, int N, int nsb)
{
    const int b = blockIdx.x;
    const int cnt = bcnt[b];
    if (cnt == 0) return;
    const int k = b / nsb;
    const int wave = threadIdx.x >> 6, lane = threadIdx.x & 63;
    const int lrow = lane & 15, lhi = lane >> 4;
    const int2* pb = pairs + (size_t)b * CAP;

    bf16x8 bfr[2][4];
    #pragma unroll
    for (int nf = 0; nf < 2; ++nf)
        #pragma unroll
        for (int ks = 0; ks < 4; ++ks)
            bfr[nf][ks] = *reinterpret_cast<const bf16x8*>(
                Wp + ((size_t)((k * 4 + ks) * 8 + wave * 2 + nf) * 64 + lane) * 8);

    for (int t0 = 0; t0 < cnt; t0 += 64) {
        int srcs[4];
        #pragma unroll
        for (int mf = 0; mf < 4; ++mf) {
            int slot = t0 + mf * 16 + lrow;
            srcs[mf] = (slot < cnt) ? pb[slot].y : -1;
        }

        f32x4 zero = {0.f, 0.f, 0.f, 0.f};
        f32x4 acc[4][2];
        #pragma unroll
        for (int mf = 0; mf < 4; ++mf) { acc[mf][0] = zero; acc[mf][1] = zero; }

        #pragma unroll
        for (int ks = 0; ks < 4; ++ks)
            #pragma unroll
            for (int mf = 0; mf < 4; ++mf) {
                bf16x8 a = {0,0,0,0,0,0,0,0};
                if (srcs[mf] >= 0) {
                    const float* fr = feats + (size_t)srcs[mf] * CIN + ks * 32 + lhi * 8;
                    float4 x = *reinterpret_cast<const float4*>(fr);
                    float4 y = *reinterpret_cast<const float4*>(fr + 4);
                    a = bf16x8{ f2bf(x.x), f2bf(x.y), f2bf(x.z), f2bf(x.w),
                                f2bf(y.x), f2bf(y.y), f2bf(y.z), f2bf(y.w) };
                }
                acc[mf][0] = __builtin_amdgcn_mfma_f32_16x16x32_bf16(a, bfr[0][ks], acc[mf][0], 0, 0, 0);
                acc[mf][1] = __builtin_amdgcn_mfma_f32_16x16x32_bf16(a, bfr[1][ks], acc[mf][1], 0, 0, 0);
            }

        #pragma unroll
        for (int mf = 0; mf < 4; ++mf)
            #pragma unroll
            for (int j = 0; j < 4; ++j) {
                int slot = t0 + mf * 16 + lhi * 4 + j;
                if (slot >= cnt) continue;
                short* dst = partial + ((size_t)b * CAP + slot) * COUT + wave * 32 + lrow;
                dst[0]  = f2bf(acc[mf][0][j]);
                dst[16] = f2bf(acc[mf][1][j]);
            }
    }
}

// ============================================================================
// K3 center + reduce: per 64-row tile.
//  (a) 26 searcher lanes binary-search their (k, sb) bucket (n-sorted) for
//      rows in [tile0, tile0+64) -> LDS list (k-major, deterministic).
//  (b) center MFMA with IDENTITY gather (contiguous fp32 feats reads).
//  (c) acc -> LDS Atile (stride 129 floats: bank-conflict-free by row).
//  (d) row-owner threads (4/row) add bf16 partial rows in fixed k order.
//  (e) single coalesced fp32 write of out. No atomics, no out re-read.
// ============================================================================
__global__ __launch_bounds__(256) void center_reduce(
    const float* __restrict__ feats, const short* __restrict__ Wp13,
    const int2* __restrict__ pairs, const int* __restrict__ bcnt,
    const short* __restrict__ partial, float* __restrict__ out, int N, int nsb)
{
    __shared__ float Atile[64][129];
    __shared__ int2 lst[KK][16];
    __shared__ int  lcnt[KK];

    const int tile0 = blockIdx.x * 64;
    const int t = threadIdx.x;

    // ---- (a) bucket search ----
    if (t < KK) {
        lcnt[t] = 0;
        if (t != 13) {
            int b = t * nsb + (tile0 >> 11);
            int cnt = bcnt[b];
            const int2* pb = pairs + (size_t)b * CAP;
            int lo = 0, hi = cnt;
            while (lo < hi) {
                int mid = (lo + hi) >> 1;
                if (pb[mid].x < tile0) lo = mid + 1; else hi = mid;
            }
            int c = 0;
            while (lo < cnt && c < 16) {
                int2 p = pb[lo];
                if (p.x >= tile0 + 64) break;
                lst[t][c] = make_int2(p.x - tile0, b * CAP + lo);
                ++c; ++lo;
            }
            lcnt[t] = c;
        }
    }

    // ---- (b) center MFMA, identity gather ----
    const int wave = t >> 6, lane = t & 63;
    const int lrow = lane & 15, lhi = lane >> 4;

    bf16x8 bfr[2][4];
    #pragma unroll
    for (int nf = 0; nf < 2; ++nf)
        #pragma unroll
        for (int ks = 0; ks < 4; ++ks)
            bfr[nf][ks] = *reinterpret_cast<const bf16x8*>(
                Wp13 + ((size_t)(ks * 8 + wave * 2 + nf) * 64 + lane) * 8);

    f32x4 zero = {0.f, 0.f, 0.f, 0.f};
    f32x4 acc[4][2];
    #pragma unroll
    for (int mf = 0; mf < 4; ++mf) { acc[mf][0] = zero; acc[mf][1] = zero; }

    #pragma unroll
    for (int ks = 0; ks < 4; ++ks)
        #pragma unroll
        for (int mf = 0; mf < 4; ++mf) {
            int r = tile0 + mf * 16 + lrow;
            bf16x8 a = {0,0,0,0,0,0,0,0};
            if (r < N) {
                const float* fr = feats + (size_t)r * CIN + ks * 32 + lhi * 8;
                float4 x = *reinterpret_cast<const float4*>(fr);
                float4 y = *reinterpret_cast<const float4*>(fr + 4);
                a = bf16x8{ f2bf(x.x), f2bf(x.y), f2bf(x.z), f2bf(x.w),
                            f2bf(y.x), f2bf(y.y), f2bf(y.z), f2bf(y.w) };
            }
            acc[mf][0] = __builtin_amdgcn_mfma_f32_16x16x32_bf16(a, bfr[0][ks], acc[mf][0], 0, 0, 0);
            acc[mf][1] = __builtin_amdgcn_mfma_f32_16x16x32_bf16(a, bfr[1][ks], acc[mf][1], 0, 0, 0);
        }

    // ---- (c) acc -> Atile ----
    #pragma unroll
    for (int mf = 0; mf < 4; ++mf)
        #pragma unroll
        for (int nf = 0; nf < 2; ++nf)
            #pragma unroll
            for (int j = 0; j < 4; ++j)
                Atile[mf * 16 + lhi * 4 + j][wave * 32 + nf * 16 + lrow] = acc[mf][nf][j];
    __syncthreads();

    // ---- (d) per-row-owner partial adds (k-major order, race-free) ----
    const int r = t >> 2, q = t & 3;
    #pragma unroll 1
    for (int k = 0; k < KK; ++k) {
        int c = lcnt[k];
        for (int i = 0; i < c; ++i) {
            int2 e = lst[k][i];
            if (e.x != r) continue;
            const short* pr = partial + (size_t)e.y * COUT + q * 32;
            #pragma unroll
            for (int j = 0; j < 32; ++j)
                Atile[r][q * 32 + j] += bf2f(pr[j]);
        }
    }
    __syncthreads();

    // ---- (e) single coalesced out write ----
    if (tile0 + r < N) {
        float* dst = out + (size_t)(tile0 + r) * COUT + q * 32;
        #pragma unroll
        for (int j4 = 0; j4 < 8; ++j4) {
            float4 v = make_float4(Atile[r][q * 32 + j4 * 4 + 0],
                                   Atile[r][q * 32 + j4 * 4 + 1],
                                   Atile[r][q * 32 + j4 * 4 + 2],
                                   Atile[r][q * 32 + j4 * 4 + 3]);
            *reinterpret_cast<float4*>(dst + j4 * 4) = v;
        }
    }
}

// ============================================================================
// Fallback (ws too small): one block per voxel, fp32.
// ============================================================================
__global__ __launch_bounds__(128) void naive_spconv(
    const float* __restrict__ feats, const float* __restrict__ Wbase,
    const int* __restrict__ nbr, float* __restrict__ out, int N)
{
    int n  = blockIdx.x;
    int co = threadIdx.x;
    __shared__ float frow[CIN];
    float acc = 0.f;
    for (int k = 0; k < KK; ++k) {
        int src = nbr[(size_t)k * N + n];
        if (src < 0) continue;
        __syncthreads();
        frow[co] = feats[(size_t)src * CIN + co];
        __syncthreads();
        const float* Wk = Wbase + (size_t)k * CIN * COUT;
        #pragma unroll 8
        for (int ci = 0; ci < CIN; ++ci)
            acc = fmaf(frow[ci], Wk[ci * COUT + co], acc);
    }
    out[(size_t)n * COUT + co] = acc;
}

extern "C" void kernel_launch(void* const* d_in, const int* in_sizes, int n_in,
                              void* d_out, int out_size, void* d_ws, size_t ws_size,
                              hipStream_t stream) {
    const float* feats = (const float*)d_in[0];
    const float* Wb    = (const float*)d_in[1];
    const int*   nbr   = (const int*)d_in[2];
    float* out = (float*)d_out;
    const int N = in_sizes[0] / CIN;
    const int nsb = (N + 2047) >> 11;            // 2048-row superblocks
    const int nbk = KK * nsb;                    // buckets

    // ws: bcnt[nbk] | Wp bf16 27*16384 | pairs int2 nbk*CAP | partial bf16 nbk*CAP*128
    size_t off_bcnt  = 0;
    size_t off_wp    = ((size_t)nbk * 4 + 255) & ~(size_t)255;
    size_t off_pairs = (off_wp + (size_t)KK * 16384 * 2 + 255) & ~(size_t)255;
    size_t off_part  = (off_pairs + (size_t)nbk * CAP * 8 + 255) & ~(size_t)255;
    size_t need = off_part + (size_t)nbk * CAP * COUT * 2;

    if (ws_size >= need) {
        int*   bcnt  = (int*)((char*)d_ws + off_bcnt);
        short* wp    = (short*)((char*)d_ws + off_wp);
        int2*  pairs = (int2*)((char*)d_ws + off_pairs);
        short* part  = (short*)((char*)d_ws + off_part);

        prep<<<PACKB + nbk, 256, 0, stream>>>(Wb, wp, nbr, N, nsb, bcnt, pairs);
        sparse_gemm<<<nbk, 256, 0, stream>>>(feats, wp, pairs, bcnt, part, N, nsb);
        center_reduce<<<(N + 63) / 64, 256, 0, stream>>>(
            feats, wp + (size_t)13 * 16384, pairs, bcnt, part, out, N, nsb);
    } else {
        naive_spconv<<<N, 128, 0, stream>>>(feats, Wb, nbr, out, N);
    }
}

// Round 8
// 68.235 us; speedup vs baseline: 1.1546x; 1.1546x over previous
//
#include <hip/hip_runtime.h>
#include <stddef.h>

#define CIN  128
#define COUT 128
#define KK   27
#define CAP  256     // pair capacity per (k, 2048-row superblock); mean 49, ~30 sigma
#define EMAX 96      // entries per 64-row output tile; mean ~40, ~9 sigma

typedef short bf16x8 __attribute__((ext_vector_type(8)));
typedef float f32x4  __attribute__((ext_vector_type(4)));

__device__ __forceinline__ short f2bf(float f) {
    unsigned u = __float_as_uint(f);
    unsigned r = (u + 0x7fffu + ((u >> 16) & 1u)) >> 16;
    return (short)r;
}
__device__ __forceinline__ float bf2f(short s) {
    unsigned u = ((unsigned)(unsigned short)s) << 16;
    return __uint_as_float(u);
}

#define PACK_UNITS (KK * 4 * 8 * 64)          // 55296 B-fragment slots
#define PACKB ((PACK_UNITS + 255) / 256)      // 216 blocks

// ============================================================================
// K1 pack_W: W fp32 -> bf16 MFMA B-fragment order. MUST be its own kernel:
// consumers read Wp, and cross-block ordering within a launch is undefined.
//   Wp[(((k*4+ks)*8+nf)*64+lane)*8+j] = bf16(W[k][ks*32+(lane>>4)*8+j][nf*16+(lane&15)])
// ============================================================================
__global__ __launch_bounds__(256) void pack_W(
    const float* __restrict__ W, short* __restrict__ Wp)
{
    int fl = blockIdx.x * 256 + threadIdx.x;
    if (fl >= PACK_UNITS) return;
    int lane = fl & 63, nf = (fl >> 6) & 7, ks = (fl >> 9) & 3, k = fl >> 11;
    int col  = nf * 16 + (lane & 15);
    int krow = ks * 32 + (lane >> 4) * 8;
    bf16x8 v;
    #pragma unroll
    for (int j = 0; j < 8; ++j)
        v[j] = f2bf(W[((size_t)k * CIN + krow + j) * COUT + col]);
    *reinterpret_cast<bf16x8*>(Wp + (size_t)fl * 8) = v;
}

// ============================================================================
// K2 bucket_gemm: per (k, 2048-row superblock) bucket:
//   (a) ballot-prefix compaction of (n, src) pairs -> LDS + global (n-sorted),
//   (b) direct-gather bf16 MFMA over the bucket's rows -> bf16 partial rows.
// Block-local only: no atomics, no cross-block scan.
// k==13 skipped (center is identity: nbr[13][n]==n by construction).
// ============================================================================
__global__ __launch_bounds__(256) void bucket_gemm(
    const short* __restrict__ Wp, const int* __restrict__ nbr,
    const float* __restrict__ feats, int N, int nsb,
    int* __restrict__ bcnt, int2* __restrict__ pairs, short* __restrict__ partial)
{
    const int b = blockIdx.x;                  // bucket = k*nsb + sb
    const int k = b / nsb, sb = b - k * nsb;
    if (k == 13) { if (threadIdx.x == 0) bcnt[b] = 0; return; }

    __shared__ int2 plds[CAP];
    __shared__ int wtot[4];
    __shared__ int sbase, scap;

    const int wave = threadIdx.x >> 6, lane = threadIdx.x & 63;

    // B-fragments early (Wp packed by K1; latency overlaps compaction)
    bf16x8 bfr[2][4];
    #pragma unroll
    for (int nf = 0; nf < 2; ++nf)
        #pragma unroll
        for (int ks = 0; ks < 4; ++ks)
            bfr[nf][ks] = *reinterpret_cast<const bf16x8*>(
                Wp + ((size_t)((k * 4 + ks) * 8 + wave * 2 + nf) * 64 + lane) * 8);

    // ---- (a) compaction ----
    if (threadIdx.x == 0) sbase = 0;
    __syncthreads();
    const int* nk = nbr + (size_t)k * N;
    for (int c = 0; c < 8; ++c) {
        int n = sb * 2048 + c * 256 + threadIdx.x;
        int src = (n < N) ? nk[n] : -1;
        bool valid = (src >= 0);
        unsigned long long m = __ballot(valid);
        if (lane == 0) wtot[wave] = __popcll(m);
        __syncthreads();
        int off = sbase;
        for (int w = 0; w < wave; ++w) off += wtot[w];
        off += __popcll(m & ((1ull << lane) - 1ull));
        if (valid && off < CAP) {
            plds[off] = make_int2(n, src);
            pairs[(size_t)b * CAP + off] = make_int2(n, src);
        }
        __syncthreads();
        if (threadIdx.x == 0) sbase += wtot[0] + wtot[1] + wtot[2] + wtot[3];
        __syncthreads();
    }
    if (threadIdx.x == 0) {
        int c = (sbase < CAP) ? sbase : CAP;
        bcnt[b] = c; scap = c;
    }
    __syncthreads();
    const int cnt = scap;
    if (cnt == 0) return;

    // ---- (b) direct-gather MFMA ----
    const int lrow = lane & 15, lhi = lane >> 4;
    for (int t0 = 0; t0 < cnt; t0 += 64) {
        int srcs[4];
        #pragma unroll
        for (int mf = 0; mf < 4; ++mf) {
            int slot = t0 + mf * 16 + lrow;
            srcs[mf] = (slot < cnt) ? plds[slot].y : -1;
        }
        f32x4 zero = {0.f, 0.f, 0.f, 0.f};
        f32x4 acc[4][2];
        #pragma unroll
        for (int mf = 0; mf < 4; ++mf) { acc[mf][0] = zero; acc[mf][1] = zero; }

        #pragma unroll
        for (int ks = 0; ks < 4; ++ks)
            #pragma unroll
            for (int mf = 0; mf < 4; ++mf) {
                bf16x8 a = {0,0,0,0,0,0,0,0};
                if (srcs[mf] >= 0) {
                    const float* fr = feats + (size_t)srcs[mf] * CIN + ks * 32 + lhi * 8;
                    float4 x = *reinterpret_cast<const float4*>(fr);
                    float4 y = *reinterpret_cast<const float4*>(fr + 4);
                    a = bf16x8{ f2bf(x.x), f2bf(x.y), f2bf(x.z), f2bf(x.w),
                                f2bf(y.x), f2bf(y.y), f2bf(y.z), f2bf(y.w) };
                }
                acc[mf][0] = __builtin_amdgcn_mfma_f32_16x16x32_bf16(a, bfr[0][ks], acc[mf][0], 0, 0, 0);
                acc[mf][1] = __builtin_amdgcn_mfma_f32_16x16x32_bf16(a, bfr[1][ks], acc[mf][1], 0, 0, 0);
            }

        #pragma unroll
        for (int mf = 0; mf < 4; ++mf)
            #pragma unroll
            for (int j = 0; j < 4; ++j) {
                int slot = t0 + mf * 16 + lhi * 4 + j;
                if (slot >= cnt) continue;
                short* dst = partial + ((size_t)b * CAP + slot) * COUT + wave * 32 + lrow;
                dst[0]  = f2bf(acc[mf][0][j]);
                dst[16] = f2bf(acc[mf][1][j]);
            }
    }
}

// ============================================================================
// K3 center + reduce, per 64-row tile:
//  (a) 26 searcher lanes binary-search their n-sorted bucket for the tile
//      window (runs concurrent with (b));
//  (b) center MFMA, IDENTITY gather (contiguous fp32 feats reads);
//  (c) flat k-major entry list (thread-0 scan + searcher scatter);
//  (d) cooperative Pbuf staging: 16 thr x 16B vectorized loads per entry;
//  (e) reduce INTO acc REGISTERS: uniform scalar branches select static
//      acc[mf][nf][j]; 2 broadcast LDS reads + 2 selects per entry;
//  (f) out written once from registers. No atomics, no LDS conflicts.
// ============================================================================
__global__ __launch_bounds__(256) void center_reduce(
    const float* __restrict__ feats, const short* __restrict__ Wp13,
    const int2* __restrict__ pairs, const int* __restrict__ bcnt,
    const short* __restrict__ partial, float* __restrict__ out, int N, int nsb)
{
    __shared__ short Pbuf[EMAX][136];
    __shared__ int erow[EMAX], eidx[EMAX];
    __shared__ int scnt[KK], sstart[KK], soff[KK];
    __shared__ int eTotS;

    const int tile0 = blockIdx.x * 64;
    const int t = threadIdx.x;

    // ---- (a) bucket window search ----
    if (t < KK) {
        scnt[t] = 0; sstart[t] = 0;
        if (t != 13) {
            int b = t * nsb + (tile0 >> 11);
            int cnt = bcnt[b];
            const int2* pb = pairs + (size_t)b * CAP;
            int lo = 0, hi = cnt;
            while (lo < hi) {
                int mid = (lo + hi) >> 1;
                if (pb[mid].x < tile0) lo = mid + 1; else hi = mid;
            }
            int c = 0, l2 = lo;
            while (l2 < cnt && pb[l2].x < tile0 + 64) { ++c; ++l2; }
            scnt[t] = c; sstart[t] = lo;
        }
    }

    // ---- (b) center MFMA (identity gather) ----
    const int wave = t >> 6, lane = t & 63;
    const int lrow = lane & 15, lhi = lane >> 4;

    bf16x8 bfr[2][4];
    #pragma unroll
    for (int nf = 0; nf < 2; ++nf)
        #pragma unroll
        for (int ks = 0; ks < 4; ++ks)
            bfr[nf][ks] = *reinterpret_cast<const bf16x8*>(
                Wp13 + ((size_t)(ks * 8 + wave * 2 + nf) * 64 + lane) * 8);

    f32x4 zero = {0.f, 0.f, 0.f, 0.f};
    f32x4 acc[4][2];
    #pragma unroll
    for (int mf = 0; mf < 4; ++mf) { acc[mf][0] = zero; acc[mf][1] = zero; }

    #pragma unroll
    for (int ks = 0; ks < 4; ++ks)
        #pragma unroll
        for (int mf = 0; mf < 4; ++mf) {
            int r = tile0 + mf * 16 + lrow;
            bf16x8 a = {0,0,0,0,0,0,0,0};
            if (r < N) {
                const float* fr = feats + (size_t)r * CIN + ks * 32 + lhi * 8;
                float4 x = *reinterpret_cast<const float4*>(fr);
                float4 y = *reinterpret_cast<const float4*>(fr + 4);
                a = bf16x8{ f2bf(x.x), f2bf(x.y), f2bf(x.z), f2bf(x.w),
                            f2bf(y.x), f2bf(y.y), f2bf(y.z), f2bf(y.w) };
            }
            acc[mf][0] = __builtin_amdgcn_mfma_f32_16x16x32_bf16(a, bfr[0][ks], acc[mf][0], 0, 0, 0);
            acc[mf][1] = __builtin_amdgcn_mfma_f32_16x16x32_bf16(a, bfr[1][ks], acc[mf][1], 0, 0, 0);
        }
    __syncthreads();

    // ---- (c) flat k-major entry list ----
    if (t == 0) {
        int a = 0;
        #pragma unroll 1
        for (int k = 0; k < KK; ++k) {
            int c = scnt[k];
            if (a + c > EMAX) c = EMAX - a;
            scnt[k] = c; soff[k] = a; a += c;
        }
        eTotS = a;
    }
    __syncthreads();
    if (t < KK) {
        int b = t * nsb + (tile0 >> 11);
        const int2* pb = pairs + (size_t)b * CAP;
        int c = scnt[t], o = soff[t], s0 = sstart[t];
        for (int i = 0; i < c; ++i) {
            erow[o + i] = pb[s0 + i].x - tile0;
            eidx[o + i] = b * CAP + s0 + i;
        }
    }
    __syncthreads();
    const int eTot = eTotS;

    // ---- (d) cooperative Pbuf staging (16 thr x 16B per entry row) ----
    for (int e = t >> 4; e < eTot; e += 16) {
        int sub = t & 15;
        *reinterpret_cast<bf16x8*>(&Pbuf[e][sub * 8]) =
            *reinterpret_cast<const bf16x8*>(partial + (size_t)eidx[e] * COUT + sub * 8);
    }
    __syncthreads();

    // ---- (e) register reduce: uniform branches, static acc indices ----
    #pragma unroll 1
    for (int e = 0; e < eTot; ++e) {
        int rr = __builtin_amdgcn_readfirstlane(erow[e]);
        float p0 = bf2f(Pbuf[e][wave * 32 + lrow]);
        float p1 = bf2f(Pbuf[e][wave * 32 + 16 + lrow]);
        bool act = (lhi == ((rr >> 2) & 3));
        float a0 = act ? p0 : 0.f;
        float a1 = act ? p1 : 0.f;
        #pragma unroll
        for (int mf = 0; mf < 4; ++mf) {
            if ((rr >> 4) != mf) continue;
            #pragma unroll
            for (int j = 0; j < 4; ++j) {
                if ((rr & 3) != j) continue;
                acc[mf][0][j] += a0;
                acc[mf][1][j] += a1;
            }
        }
    }

    // ---- (f) store out from registers ----
    #pragma unroll
    for (int mf = 0; mf < 4; ++mf)
        #pragma unroll
        for (int nf = 0; nf < 2; ++nf)
            #pragma unroll
            for (int j = 0; j < 4; ++j) {
                int r = tile0 + mf * 16 + lhi * 4 + j;
                if (r < N)
                    out[(size_t)r * COUT + wave * 32 + nf * 16 + lrow] = acc[mf][nf][j];
            }
}

// ============================================================================
// Fallback (ws too small): one block per voxel, fp32.
// ============================================================================
__global__ __launch_bounds__(128) void naive_spconv(
    const float* __restrict__ feats, const float* __restrict__ Wbase,
    const int* __restrict__ nbr, float* __restrict__ out, int N)
{
    int n  = blockIdx.x;
    int co = threadIdx.x;
    __shared__ float frow[CIN];
    float acc = 0.f;
    for (int k = 0; k < KK; ++k) {
        int src = nbr[(size_t)k * N + n];
        if (src < 0) continue;
        __syncthreads();
        frow[co] = feats[(size_t)src * CIN + co];
        __syncthreads();
        const float* Wk = Wbase + (size_t)k * CIN * COUT;
        #pragma unroll 8
        for (int ci = 0; ci < CIN; ++ci)
            acc = fmaf(frow[ci], Wk[ci * COUT + co], acc);
    }
    out[(size_t)n * COUT + co] = acc;
}

extern "C" void kernel_launch(void* const* d_in, const int* in_sizes, int n_in,
                              void* d_out, int out_size, void* d_ws, size_t ws_size,
                              hipStream_t stream) {
    const float* feats = (const float*)d_in[0];
    const float* Wb    = (const float*)d_in[1];
    const int*   nbr   = (const int*)d_in[2];
    float* out = (float*)d_out;
    const int N = in_sizes[0] / CIN;
    const int nsb = (N + 2047) >> 11;            // 2048-row superblocks
    const int nbk = KK * nsb;                    // buckets

    // ws: bcnt[nbk] | Wp bf16 27*16384 | pairs int2 nbk*CAP | partial bf16 nbk*CAP*128
    size_t off_bcnt  = 0;
    size_t off_wp    = ((size_t)nbk * 4 + 255) & ~(size_t)255;
    size_t off_pairs = (off_wp + (size_t)KK * 16384 * 2 + 255) & ~(size_t)255;
    size_t off_part  = (off_pairs + (size_t)nbk * CAP * 8 + 255) & ~(size_t)255;
    size_t need = off_part + (size_t)nbk * CAP * COUT * 2;

    if (ws_size >= need) {
        int*   bcnt  = (int*)((char*)d_ws + off_bcnt);
        short* wp    = (short*)((char*)d_ws + off_wp);
        int2*  pairs = (int2*)((char*)d_ws + off_pairs);
        short* part  = (short*)((char*)d_ws + off_part);

        pack_W<<<PACKB, 256, 0, stream>>>(Wb, wp);
        bucket_gemm<<<nbk, 256, 0, stream>>>(wp, nbr, feats, N, nsb, bcnt, pairs, part);
        center_reduce<<<(N + 63) / 64, 256, 0, stream>>>(
            feats, wp + (size_t)13 * 16384, pairs, bcnt, part, out, N, nsb);
    } else {
        naive_spconv<<<N, 128, 0, stream>>>(feats, Wb, nbr, out, N);
    }
}

// Round 9
// 68.229 us; speedup vs baseline: 1.1547x; 1.0001x over previous
//
#include <hip/hip_runtime.h>
#include <stddef.h>

#define CIN  128
#define COUT 128
#define KK   27
#define CAP  256     // pair capacity per (k, 2048-row superblock); mean 49, ~30 sigma
#define EMAX 96      // entries per 64-row output tile; mean ~40, ~9 sigma

typedef short bf16x8 __attribute__((ext_vector_type(8)));
typedef float f32x4  __attribute__((ext_vector_type(4)));

__device__ __forceinline__ short f2bf(float f) {
    unsigned u = __float_as_uint(f);
    unsigned r = (u + 0x7fffu + ((u >> 16) & 1u)) >> 16;
    return (short)r;
}
__device__ __forceinline__ float bf2f(short s) {
    unsigned u = ((unsigned)(unsigned short)s) << 16;
    return __uint_as_float(u);
}

#define PACK_UNITS (KK * 4 * 8 * 64)          // 55296 B-fragment slots
#define PACKB ((PACK_UNITS + 255) / 256)      // 216 blocks

// ============================================================================
// K1 pack_W: W fp32 -> bf16 MFMA B-fragment order (own kernel: consumers read
// Wp and cross-block ordering within a launch is undefined).
//   Wp[(((k*4+ks)*8+nf)*64+lane)*8+j] = bf16(W[k][ks*32+(lane>>4)*8+j][nf*16+(lane&15)])
// ============================================================================
__global__ __launch_bounds__(256) void pack_W(
    const float* __restrict__ W, short* __restrict__ Wp)
{
    int fl = blockIdx.x * 256 + threadIdx.x;
    if (fl >= PACK_UNITS) return;
    int lane = fl & 63, nf = (fl >> 6) & 7, ks = (fl >> 9) & 3, k = fl >> 11;
    int col  = nf * 16 + (lane & 15);
    int krow = ks * 32 + (lane >> 4) * 8;
    bf16x8 v;
    #pragma unroll
    for (int j = 0; j < 8; ++j)
        v[j] = f2bf(W[((size_t)k * CIN + krow + j) * COUT + col]);
    *reinterpret_cast<bf16x8*>(Wp + (size_t)fl * 8) = v;
}

// ============================================================================
// K2 bucket_gemm, per (k, 2048-row superblock) bucket:
//   (a) ballot-prefix compaction of (n, src) pairs -> LDS (n-sorted) AND a
//       COALESCED pos[k*N+n] write (slot index or -1) for the reduce kernel;
//   (b) direct-gather bf16 MFMA over the bucket rows -> bf16 partial rows.
// Block-local only: no atomics, no cross-block scan, no global pair lists.
// k==13 skipped (center is identity: nbr[13][n]==n by construction).
// ============================================================================
__global__ __launch_bounds__(256) void bucket_gemm(
    const short* __restrict__ Wp, const int* __restrict__ nbr,
    const float* __restrict__ feats, int N, int nsb,
    int* __restrict__ pos, short* __restrict__ partial)
{
    const int b = blockIdx.x;                  // bucket = k*nsb + sb
    const int k = b / nsb, sb = b - k * nsb;
    if (k == 13) return;

    __shared__ int2 plds[CAP];
    __shared__ int wtot[4];
    __shared__ int sbase, scap;

    const int wave = threadIdx.x >> 6, lane = threadIdx.x & 63;

    // ---- (a) compaction + coalesced pos writes ----
    if (threadIdx.x == 0) sbase = 0;
    __syncthreads();
    const int* nk   = nbr + (size_t)k * N;
    int*       posk = pos + (size_t)k * N;
    for (int c = 0; c < 8; ++c) {
        int n = sb * 2048 + c * 256 + threadIdx.x;
        int src = (n < N) ? nk[n] : -1;
        bool valid = (src >= 0);
        unsigned long long m = __ballot(valid);
        if (lane == 0) wtot[wave] = __popcll(m);
        __syncthreads();
        int off = sbase;
        for (int w = 0; w < wave; ++w) off += wtot[w];
        off += __popcll(m & ((1ull << lane) - 1ull));
        bool kept = valid && (off < CAP);
        if (kept) plds[off] = make_int2(n, src);
        if (n < N) posk[n] = kept ? (b * CAP + off) : -1;
        __syncthreads();
        if (threadIdx.x == 0) sbase += wtot[0] + wtot[1] + wtot[2] + wtot[3];
        __syncthreads();
    }
    if (threadIdx.x == 0) scap = (sbase < CAP) ? sbase : CAP;
    __syncthreads();
    const int cnt = scap;
    if (cnt == 0) return;

    // B-fragments after compaction (barriers above no longer drain these loads)
    bf16x8 bfr[2][4];
    #pragma unroll
    for (int nf = 0; nf < 2; ++nf)
        #pragma unroll
        for (int ks = 0; ks < 4; ++ks)
            bfr[nf][ks] = *reinterpret_cast<const bf16x8*>(
                Wp + ((size_t)((k * 4 + ks) * 8 + wave * 2 + nf) * 64 + lane) * 8);

    // ---- (b) direct-gather MFMA ----
    const int lrow = lane & 15, lhi = lane >> 4;
    for (int t0 = 0; t0 < cnt; t0 += 64) {
        int srcs[4];
        #pragma unroll
        for (int mf = 0; mf < 4; ++mf) {
            int slot = t0 + mf * 16 + lrow;
            srcs[mf] = (slot < cnt) ? plds[slot].y : -1;
        }
        f32x4 zero = {0.f, 0.f, 0.f, 0.f};
        f32x4 acc[4][2];
        #pragma unroll
        for (int mf = 0; mf < 4; ++mf) { acc[mf][0] = zero; acc[mf][1] = zero; }

        #pragma unroll
        for (int ks = 0; ks < 4; ++ks)
            #pragma unroll
            for (int mf = 0; mf < 4; ++mf) {
                bf16x8 a = {0,0,0,0,0,0,0,0};
                if (srcs[mf] >= 0) {
                    const float* fr = feats + (size_t)srcs[mf] * CIN + ks * 32 + lhi * 8;
                    float4 x = *reinterpret_cast<const float4*>(fr);
                    float4 y = *reinterpret_cast<const float4*>(fr + 4);
                    a = bf16x8{ f2bf(x.x), f2bf(x.y), f2bf(x.z), f2bf(x.w),
                                f2bf(y.x), f2bf(y.y), f2bf(y.z), f2bf(y.w) };
                }
                acc[mf][0] = __builtin_amdgcn_mfma_f32_16x16x32_bf16(a, bfr[0][ks], acc[mf][0], 0, 0, 0);
                acc[mf][1] = __builtin_amdgcn_mfma_f32_16x16x32_bf16(a, bfr[1][ks], acc[mf][1], 0, 0, 0);
            }

        #pragma unroll
        for (int mf = 0; mf < 4; ++mf)
            #pragma unroll
            for (int j = 0; j < 4; ++j) {
                int slot = t0 + mf * 16 + lhi * 4 + j;
                if (slot >= cnt) continue;
                short* dst = partial + ((size_t)b * CAP + slot) * COUT + wave * 32 + lrow;
                dst[0]  = f2bf(acc[mf][0][j]);
                dst[16] = f2bf(acc[mf][1][j]);
            }
    }
}

// ============================================================================
// K3 center + reduce, per 64-row tile:
//  (a) wave-parallel list build from pos: wave w handles k = rd*4+w; lane =
//      row. Coalesced reads + ballot compact -> k-major (erow, slot) list.
//      No global searches, no pointer chases.
//  (d) cooperative Pbuf staging ISSUED EARLY (hides under center MFMA);
//  (b) center MFMA, IDENTITY gather (contiguous fp32 feats reads);
//  (e) register reduce, BATCHED x4: 4 entries' LDS reads issued together,
//      then 4 uniform scalar-branch applies into static acc[mf][nf][j];
//  (f) out written once from registers. No atomics, no LDS conflicts.
// ============================================================================
__global__ __launch_bounds__(256) void center_reduce(
    const float* __restrict__ feats, const short* __restrict__ Wp13,
    const int* __restrict__ pos, const short* __restrict__ partial,
    float* __restrict__ out, int N)
{
    __shared__ short Pbuf[EMAX][136];
    __shared__ short erowL[EMAX];
    __shared__ int   eidxL[EMAX];
    __shared__ int   kcnt[KK], koff[KK];
    __shared__ int   eTotS;

    const int tile0 = blockIdx.x * 64;
    const int t = threadIdx.x;
    const int wave = t >> 6, lane = t & 63;
    const int lrow = lane & 15, lhi = lane >> 4;

    // ---- (a) list build from pos ----
    int myv[7], mypfx[7];
    #pragma unroll
    for (int rd = 0; rd < 7; ++rd) {
        int k = rd * 4 + wave;
        int v = -1;
        if (k < KK && k != 13 && tile0 + lane < N)
            v = pos[(size_t)k * N + tile0 + lane];
        bool valid = (v >= 0);
        unsigned long long m = __ballot(valid);
        myv[rd] = v;
        mypfx[rd] = __popcll(m & ((1ull << lane) - 1ull));
        if (k < KK && lane == 0) kcnt[k] = __popcll(m);
    }
    __syncthreads();
    if (t == 0) {
        int a = 0;
        for (int k = 0; k < KK; ++k) { koff[k] = a; a += kcnt[k]; }
        eTotS = (a < EMAX) ? a : EMAX;
    }
    __syncthreads();
    #pragma unroll
    for (int rd = 0; rd < 7; ++rd) {
        int k = rd * 4 + wave;
        if (k < KK && myv[rd] >= 0) {
            int s = koff[k] + mypfx[rd];
            if (s < EMAX) { erowL[s] = (short)lane; eidxL[s] = myv[rd]; }
        }
    }
    __syncthreads();
    const int eTot = eTotS;

    // ---- (d) Pbuf staging issued early: latency hides under (b) ----
    for (int e = t >> 4; e < eTot; e += 16) {
        int sub = t & 15;
        *reinterpret_cast<bf16x8*>(&Pbuf[e][sub * 8]) =
            *reinterpret_cast<const bf16x8*>(partial + (size_t)eidxL[e] * COUT + sub * 8);
    }

    // ---- (b) center MFMA (identity gather) ----
    bf16x8 bfr[2][4];
    #pragma unroll
    for (int nf = 0; nf < 2; ++nf)
        #pragma unroll
        for (int ks = 0; ks < 4; ++ks)
            bfr[nf][ks] = *reinterpret_cast<const bf16x8*>(
                Wp13 + ((size_t)(ks * 8 + wave * 2 + nf) * 64 + lane) * 8);

    f32x4 zero = {0.f, 0.f, 0.f, 0.f};
    f32x4 acc[4][2];
    #pragma unroll
    for (int mf = 0; mf < 4; ++mf) { acc[mf][0] = zero; acc[mf][1] = zero; }

    #pragma unroll
    for (int ks = 0; ks < 4; ++ks)
        #pragma unroll
        for (int mf = 0; mf < 4; ++mf) {
            int r = tile0 + mf * 16 + lrow;
            bf16x8 a = {0,0,0,0,0,0,0,0};
            if (r < N) {
                const float* fr = feats + (size_t)r * CIN + ks * 32 + lhi * 8;
                float4 x = *reinterpret_cast<const float4*>(fr);
                float4 y = *reinterpret_cast<const float4*>(fr + 4);
                a = bf16x8{ f2bf(x.x), f2bf(x.y), f2bf(x.z), f2bf(x.w),
                            f2bf(y.x), f2bf(y.y), f2bf(y.z), f2bf(y.w) };
            }
            acc[mf][0] = __builtin_amdgcn_mfma_f32_16x16x32_bf16(a, bfr[0][ks], acc[mf][0], 0, 0, 0);
            acc[mf][1] = __builtin_amdgcn_mfma_f32_16x16x32_bf16(a, bfr[1][ks], acc[mf][1], 0, 0, 0);
        }
    __syncthreads();   // Pbuf staging complete

    // ---- (e) batched register reduce ----
    for (int e0 = 0; e0 < eTot; e0 += 4) {
        int rrv[4]; float p0v[4], p1v[4];
        #pragma unroll
        for (int u = 0; u < 4; ++u) {
            int e = e0 + u;
            if (e < eTot) {
                rrv[u] = erowL[e];
                p0v[u] = bf2f(Pbuf[e][wave * 32 + lrow]);
                p1v[u] = bf2f(Pbuf[e][wave * 32 + 16 + lrow]);
            } else rrv[u] = -1;
        }
        #pragma unroll
        for (int u = 0; u < 4; ++u) {
            if (rrv[u] < 0) continue;                       // uniform
            int rr = __builtin_amdgcn_readfirstlane(rrv[u]);
            bool act = (lhi == ((rr >> 2) & 3));
            float a0 = act ? p0v[u] : 0.f;
            float a1 = act ? p1v[u] : 0.f;
            #pragma unroll
            for (int mf = 0; mf < 4; ++mf) {
                if ((rr >> 4) != mf) continue;
                #pragma unroll
                for (int j = 0; j < 4; ++j) {
                    if ((rr & 3) != j) continue;
                    acc[mf][0][j] += a0;
                    acc[mf][1][j] += a1;
                }
            }
        }
    }

    // ---- (f) store out from registers ----
    #pragma unroll
    for (int mf = 0; mf < 4; ++mf)
        #pragma unroll
        for (int nf = 0; nf < 2; ++nf)
            #pragma unroll
            for (int j = 0; j < 4; ++j) {
                int r = tile0 + mf * 16 + lhi * 4 + j;
                if (r < N)
                    out[(size_t)r * COUT + wave * 32 + nf * 16 + lrow] = acc[mf][nf][j];
            }
}

// ============================================================================
// Fallback (ws too small): one block per voxel, fp32.
// ============================================================================
__global__ __launch_bounds__(128) void naive_spconv(
    const float* __restrict__ feats, const float* __restrict__ Wbase,
    const int* __restrict__ nbr, float* __restrict__ out, int N)
{
    int n  = blockIdx.x;
    int co = threadIdx.x;
    __shared__ float frow[CIN];
    float acc = 0.f;
    for (int k = 0; k < KK; ++k) {
        int src = nbr[(size_t)k * N + n];
        if (src < 0) continue;
        __syncthreads();
        frow[co] = feats[(size_t)src * CIN + co];
        __syncthreads();
        const float* Wk = Wbase + (size_t)k * CIN * COUT;
        #pragma unroll 8
        for (int ci = 0; ci < CIN; ++ci)
            acc = fmaf(frow[ci], Wk[ci * COUT + co], acc);
    }
    out[(size_t)n * COUT + co] = acc;
}

extern "C" void kernel_launch(void* const* d_in, const int* in_sizes, int n_in,
                              void* d_out, int out_size, void* d_ws, size_t ws_size,
                              hipStream_t stream) {
    const float* feats = (const float*)d_in[0];
    const float* Wb    = (const float*)d_in[1];
    const int*   nbr   = (const int*)d_in[2];
    float* out = (float*)d_out;
    const int N = in_sizes[0] / CIN;
    const int nsb = (N + 2047) >> 11;            // 2048-row superblocks
    const int nbk = KK * nsb;                    // buckets

    // ws: Wp bf16 27*16384 | pos int 27*N | partial bf16 nbk*CAP*128
    size_t off_wp   = 0;
    size_t off_pos  = ((size_t)PACK_UNITS * 8 * 2 + 255) & ~(size_t)255;
    size_t off_part = (off_pos + (size_t)KK * N * 4 + 255) & ~(size_t)255;
    size_t need = off_part + (size_t)nbk * CAP * COUT * 2;

    if (ws_size >= need) {
        short* wp   = (short*)((char*)d_ws + off_wp);
        int*   pos  = (int*)((char*)d_ws + off_pos);
        short* part = (short*)((char*)d_ws + off_part);

        pack_W<<<PACKB, 256, 0, stream>>>(Wb, wp);
        bucket_gemm<<<nbk, 256, 0, stream>>>(wp, nbr, feats, N, nsb, pos, part);
        center_reduce<<<(N + 63) / 64, 256, 0, stream>>>(
            feats, wp + (size_t)13 * 16384, pos, part, out, N);
    } else {
        naive_spconv<<<N, 128, 0, stream>>>(feats, Wb, nbr, out, N);
    }
}

// Round 10
// 61.975 us; speedup vs baseline: 1.2713x; 1.1009x over previous
//
#include <hip/hip_runtime.h>
#include <stddef.h>

#define CIN  128
#define COUT 128
#define KK   27
#define CAP  256     // pair capacity per (k, 2048-row superblock); mean 49, ~30 sigma
#define EMAX 96      // entries per 64-row output tile; mean ~40, ~9 sigma

typedef short bf16x8 __attribute__((ext_vector_type(8)));
typedef float f32x4  __attribute__((ext_vector_type(4)));

__device__ __forceinline__ short f2bf(float f) {
    unsigned u = __float_as_uint(f);
    unsigned r = (u + 0x7fffu + ((u >> 16) & 1u)) >> 16;
    return (short)r;
}
__device__ __forceinline__ float bf2f(short s) {
    unsigned u = ((unsigned)(unsigned short)s) << 16;
    return __uint_as_float(u);
}

#define PACK_UNITS (KK * 4 * 8 * 64)          // 55296 B-fragment slots
#define PACKB ((PACK_UNITS + 255) / 256)      // 216 blocks

// ============================================================================
// K1 pack_W: W fp32 -> bf16 MFMA B-fragment order (own kernel: consumers read
// Wp and cross-block ordering within a launch is undefined).
//   Wp[(((k*4+ks)*8+nf)*64+lane)*8+j] = bf16(W[k][ks*32+(lane>>4)*8+j][nf*16+(lane&15)])
// ============================================================================
__global__ __launch_bounds__(256) void pack_W(
    const float* __restrict__ W, short* __restrict__ Wp)
{
    int fl = blockIdx.x * 256 + threadIdx.x;
    if (fl >= PACK_UNITS) return;
    int lane = fl & 63, nf = (fl >> 6) & 7, ks = (fl >> 9) & 3, k = fl >> 11;
    int col  = nf * 16 + (lane & 15);
    int krow = ks * 32 + (lane >> 4) * 8;
    bf16x8 v;
    #pragma unroll
    for (int j = 0; j < 8; ++j)
        v[j] = f2bf(W[((size_t)k * CIN + krow + j) * COUT + col]);
    *reinterpret_cast<bf16x8*>(Wp + (size_t)fl * 8) = v;
}

// ============================================================================
// K2 bucket_gemm, per (k, 2048-row superblock) bucket:
//   (a) ballot-prefix compaction of (n, src) -> LDS plds (n-sorted) AND a
//       COALESCED pos[k*N+n] write (partial row index or -1);
//   (b) LDS-STAGED gather GEMM per 64-row tile: cooperative fp32 gather +
//       in-register bf16 convert -> XOR-swizzled Asub -> ds_read_b128
//       fragments -> MFMA. Decouples global latency from VGPR budget.
// Block-local only: no atomics. k==13 skipped (center handled in K3).
// ============================================================================
__global__ __launch_bounds__(256) void bucket_gemm(
    const short* __restrict__ Wp, const int* __restrict__ nbr,
    const float* __restrict__ feats, int N, int nsb,
    int* __restrict__ pos, short* __restrict__ partial)
{
    const int b = blockIdx.x;                  // bucket = k*nsb + sb
    const int k = b / nsb, sb = b - k * nsb;
    if (k == 13) return;

    __shared__ short Asub[64 * 128];
    __shared__ int2 plds[CAP];
    __shared__ int wtot[4];
    __shared__ int sbase, scap;

    const int wave = threadIdx.x >> 6, lane = threadIdx.x & 63;
    const int lrow = lane & 15, lhi = lane >> 4;

    // ---- (a) compaction + coalesced pos writes ----
    if (threadIdx.x == 0) sbase = 0;
    __syncthreads();
    const int* nk   = nbr + (size_t)k * N;
    int*       posk = pos + (size_t)k * N;
    for (int c = 0; c < 8; ++c) {
        int n = sb * 2048 + c * 256 + threadIdx.x;
        int src = (n < N) ? nk[n] : -1;
        bool valid = (src >= 0);
        unsigned long long m = __ballot(valid);
        if (lane == 0) wtot[wave] = __popcll(m);
        __syncthreads();
        int off = sbase;
        for (int w = 0; w < wave; ++w) off += wtot[w];
        off += __popcll(m & ((1ull << lane) - 1ull));
        bool kept = valid && (off < CAP);
        if (kept) plds[off] = make_int2(n, src);
        if (n < N) posk[n] = kept ? (b * CAP + off) : -1;
        __syncthreads();
        if (threadIdx.x == 0) sbase += wtot[0] + wtot[1] + wtot[2] + wtot[3];
        __syncthreads();
    }
    if (threadIdx.x == 0) scap = (sbase < CAP) ? sbase : CAP;
    __syncthreads();
    const int cnt = scap;
    if (cnt == 0) return;

    // B-fragments (Wp packed by K1; L2-hot 16B/lane)
    bf16x8 bfr[2][4];
    #pragma unroll
    for (int nf = 0; nf < 2; ++nf)
        #pragma unroll
        for (int ks = 0; ks < 4; ++ks)
            bfr[nf][ks] = *reinterpret_cast<const bf16x8*>(
                Wp + ((size_t)((k * 4 + ks) * 8 + wave * 2 + nf) * 64 + lane) * 8);

    // ---- (b) LDS-staged gather GEMM, per 64-row tile ----
    for (int t0 = 0; t0 < cnt; t0 += 64) {
        __syncthreads();                       // protect Asub from prev tile
        #pragma unroll
        for (int j = 0; j < 4; ++j) {
            int slot = threadIdx.x + 256 * j;  // 64 rows x 16 chunks
            int row = slot >> 4, cg = slot & 15;
            int srow = t0 + row;
            bf16x8 v = {0,0,0,0,0,0,0,0};
            if (srow < cnt) {
                int src = plds[srow].y;        // broadcast LDS read per 16-group
                const float* fr = feats + (size_t)src * CIN + cg * 8;
                float4 x = *reinterpret_cast<const float4*>(fr);
                float4 y = *reinterpret_cast<const float4*>(fr + 4);
                v = bf16x8{ f2bf(x.x), f2bf(x.y), f2bf(x.z), f2bf(x.w),
                            f2bf(y.x), f2bf(y.y), f2bf(y.z), f2bf(y.w) };
            }
            int sw = cg ^ (row & 7);
            *reinterpret_cast<bf16x8*>(&Asub[row * 128 + sw * 8]) = v;
        }
        __syncthreads();

        f32x4 zero = {0.f, 0.f, 0.f, 0.f};
        f32x4 acc[4][2];
        #pragma unroll
        for (int mf = 0; mf < 4; ++mf) { acc[mf][0] = zero; acc[mf][1] = zero; }

        #pragma unroll
        for (int ks = 0; ks < 4; ++ks)
            #pragma unroll
            for (int mf = 0; mf < 4; ++mf) {
                int row = mf * 16 + lrow;
                int sw = (ks * 4 + lhi) ^ (lrow & 7);
                bf16x8 a = *reinterpret_cast<const bf16x8*>(&Asub[row * 128 + sw * 8]);
                acc[mf][0] = __builtin_amdgcn_mfma_f32_16x16x32_bf16(a, bfr[0][ks], acc[mf][0], 0, 0, 0);
                acc[mf][1] = __builtin_amdgcn_mfma_f32_16x16x32_bf16(a, bfr[1][ks], acc[mf][1], 0, 0, 0);
            }

        #pragma unroll
        for (int mf = 0; mf < 4; ++mf)
            #pragma unroll
            for (int j = 0; j < 4; ++j) {
                int slot = t0 + mf * 16 + lhi * 4 + j;
                if (slot >= cnt) continue;
                short* dst = partial + ((size_t)b * CAP + slot) * COUT + wave * 32 + lrow;
                dst[0]  = f2bf(acc[mf][0][j]);
                dst[16] = f2bf(acc[mf][1][j]);
            }
    }
}

// ============================================================================
// K3 center + reduce, per 64-row tile:
//  (a) wave-parallel list build from pos (coalesced + ballot compact);
//  (d) cooperative Pbuf staging issued early (hides under (b));
//  (b) center MFMA via LDS-staged A-tile: coalesced fp32 reads (IDENTITY
//      gather: nbr[13][n]==n), in-register bf16 convert, XOR-swizzled Asub,
//      ds_read_b128 fragments;
//  (e) batched register reduce (uniform branches, static acc indices);
//  (f) single out write from registers. No atomics, no conflicts.
// ============================================================================
__global__ __launch_bounds__(256) void center_reduce(
    const float* __restrict__ feats, const short* __restrict__ Wp13,
    const int* __restrict__ pos, const short* __restrict__ partial,
    float* __restrict__ out, int N)
{
    __shared__ short Asub[64 * 128];
    __shared__ short Pbuf[EMAX][136];
    __shared__ short erowL[EMAX];
    __shared__ int   eidxL[EMAX];
    __shared__ int   kcnt[KK], koff[KK];
    __shared__ int   eTotS;

    const int tile0 = blockIdx.x * 64;
    const int t = threadIdx.x;
    const int wave = t >> 6, lane = t & 63;
    const int lrow = lane & 15, lhi = lane >> 4;

    // ---- (a) list build from pos ----
    int myv[7], mypfx[7];
    #pragma unroll
    for (int rd = 0; rd < 7; ++rd) {
        int k = rd * 4 + wave;
        int v = -1;
        if (k < KK && k != 13 && tile0 + lane < N)
            v = pos[(size_t)k * N + tile0 + lane];
        bool valid = (v >= 0);
        unsigned long long m = __ballot(valid);
        myv[rd] = v;
        mypfx[rd] = __popcll(m & ((1ull << lane) - 1ull));
        if (k < KK && lane == 0) kcnt[k] = __popcll(m);
    }
    __syncthreads();
    if (t == 0) {
        int a = 0;
        for (int k = 0; k < KK; ++k) { koff[k] = a; a += kcnt[k]; }
        eTotS = (a < EMAX) ? a : EMAX;
    }
    __syncthreads();
    #pragma unroll
    for (int rd = 0; rd < 7; ++rd) {
        int k = rd * 4 + wave;
        if (k < KK && myv[rd] >= 0) {
            int s = koff[k] + mypfx[rd];
            if (s < EMAX) { erowL[s] = (short)lane; eidxL[s] = myv[rd]; }
        }
    }
    __syncthreads();
    const int eTot = eTotS;

    // ---- (d) Pbuf staging issued early: latency hides under (b) ----
    for (int e = t >> 4; e < eTot; e += 16) {
        int sub = t & 15;
        *reinterpret_cast<bf16x8*>(&Pbuf[e][sub * 8]) =
            *reinterpret_cast<const bf16x8*>(partial + (size_t)eidxL[e] * COUT + sub * 8);
    }

    // ---- (b) center A-tile staging (identity gather, coalesced) ----
    #pragma unroll
    for (int j = 0; j < 4; ++j) {
        int slot = t + 256 * j;
        int row = slot >> 4, cg = slot & 15;
        int r = tile0 + row;
        bf16x8 v = {0,0,0,0,0,0,0,0};
        if (r < N) {
            const float* fr = feats + (size_t)r * CIN + cg * 8;
            float4 x = *reinterpret_cast<const float4*>(fr);
            float4 y = *reinterpret_cast<const float4*>(fr + 4);
            v = bf16x8{ f2bf(x.x), f2bf(x.y), f2bf(x.z), f2bf(x.w),
                        f2bf(y.x), f2bf(y.y), f2bf(y.z), f2bf(y.w) };
        }
        int sw = cg ^ (row & 7);
        *reinterpret_cast<bf16x8*>(&Asub[row * 128 + sw * 8]) = v;
    }

    bf16x8 bfr[2][4];
    #pragma unroll
    for (int nf = 0; nf < 2; ++nf)
        #pragma unroll
        for (int ks = 0; ks < 4; ++ks)
            bfr[nf][ks] = *reinterpret_cast<const bf16x8*>(
                Wp13 + ((size_t)(ks * 8 + wave * 2 + nf) * 64 + lane) * 8);

    __syncthreads();   // Asub + Pbuf staging complete

    f32x4 zero = {0.f, 0.f, 0.f, 0.f};
    f32x4 acc[4][2];
    #pragma unroll
    for (int mf = 0; mf < 4; ++mf) { acc[mf][0] = zero; acc[mf][1] = zero; }

    #pragma unroll
    for (int ks = 0; ks < 4; ++ks)
        #pragma unroll
        for (int mf = 0; mf < 4; ++mf) {
            int row = mf * 16 + lrow;
            int sw = (ks * 4 + lhi) ^ (lrow & 7);
            bf16x8 a = *reinterpret_cast<const bf16x8*>(&Asub[row * 128 + sw * 8]);
            acc[mf][0] = __builtin_amdgcn_mfma_f32_16x16x32_bf16(a, bfr[0][ks], acc[mf][0], 0, 0, 0);
            acc[mf][1] = __builtin_amdgcn_mfma_f32_16x16x32_bf16(a, bfr[1][ks], acc[mf][1], 0, 0, 0);
        }

    // ---- (e) batched register reduce ----
    for (int e0 = 0; e0 < eTot; e0 += 4) {
        int rrv[4]; float p0v[4], p1v[4];
        #pragma unroll
        for (int u = 0; u < 4; ++u) {
            int e = e0 + u;
            if (e < eTot) {
                rrv[u] = erowL[e];
                p0v[u] = bf2f(Pbuf[e][wave * 32 + lrow]);
                p1v[u] = bf2f(Pbuf[e][wave * 32 + 16 + lrow]);
            } else rrv[u] = -1;
        }
        #pragma unroll
        for (int u = 0; u < 4; ++u) {
            if (rrv[u] < 0) continue;                       // uniform
            int rr = __builtin_amdgcn_readfirstlane(rrv[u]);
            bool act = (lhi == ((rr >> 2) & 3));
            float a0 = act ? p0v[u] : 0.f;
            float a1 = act ? p1v[u] : 0.f;
            #pragma unroll
            for (int mf = 0; mf < 4; ++mf) {
                if ((rr >> 4) != mf) continue;
                #pragma unroll
                for (int j = 0; j < 4; ++j) {
                    if ((rr & 3) != j) continue;
                    acc[mf][0][j] += a0;
                    acc[mf][1][j] += a1;
                }
            }
        }
    }

    // ---- (f) store out from registers ----
    #pragma unroll
    for (int mf = 0; mf < 4; ++mf)
        #pragma unroll
        for (int nf = 0; nf < 2; ++nf)
            #pragma unroll
            for (int j = 0; j < 4; ++j) {
                int r = tile0 + mf * 16 + lhi * 4 + j;
                if (r < N)
                    out[(size_t)r * COUT + wave * 32 + nf * 16 + lrow] = acc[mf][nf][j];
            }
}

// ============================================================================
// Fallback (ws too small): one block per voxel, fp32.
// ============================================================================
__global__ __launch_bounds__(128) void naive_spconv(
    const float* __restrict__ feats, const float* __restrict__ Wbase,
    const int* __restrict__ nbr, float* __restrict__ out, int N)
{
    int n  = blockIdx.x;
    int co = threadIdx.x;
    __shared__ float frow[CIN];
    float acc = 0.f;
    for (int k = 0; k < KK; ++k) {
        int src = nbr[(size_t)k * N + n];
        if (src < 0) continue;
        __syncthreads();
        frow[co] = feats[(size_t)src * CIN + co];
        __syncthreads();
        const float* Wk = Wbase + (size_t)k * CIN * COUT;
        #pragma unroll 8
        for (int ci = 0; ci < CIN; ++ci)
            acc = fmaf(frow[ci], Wk[ci * COUT + co], acc);
    }
    out[(size_t)n * COUT + co] = acc;
}

extern "C" void kernel_launch(void* const* d_in, const int* in_sizes, int n_in,
                              void* d_out, int out_size, void* d_ws, size_t ws_size,
                              hipStream_t stream) {
    const float* feats = (const float*)d_in[0];
    const float* Wb    = (const float*)d_in[1];
    const int*   nbr   = (const int*)d_in[2];
    float* out = (float*)d_out;
    const int N = in_sizes[0] / CIN;
    const int nsb = (N + 2047) >> 11;            // 2048-row superblocks
    const int nbk = KK * nsb;                    // buckets

    // ws: Wp bf16 27*16384 | pos int 27*N | partial bf16 nbk*CAP*128
    size_t off_wp   = 0;
    size_t off_pos  = ((size_t)PACK_UNITS * 8 * 2 + 255) & ~(size_t)255;
    size_t off_part = (off_pos + (size_t)KK * N * 4 + 255) & ~(size_t)255;
    size_t need = off_part + (size_t)nbk * CAP * COUT * 2;

    if (ws_size >= need) {
        short* wp   = (short*)((char*)d_ws + off_wp);
        int*   pos  = (int*)((char*)d_ws + off_pos);
        short* part = (short*)((char*)d_ws + off_part);

        pack_W<<<PACKB, 256, 0, stream>>>(Wb, wp);
        bucket_gemm<<<nbk, 256, 0, stream>>>(wp, nbr, feats, N, nsb, pos, part);
        center_reduce<<<(N + 63) / 64, 256, 0, stream>>>(
            feats, wp + (size_t)13 * 16384, pos, part, out, N);
    } else {
        naive_spconv<<<N, 128, 0, stream>>>(feats, Wb, nbr, out, N);
    }
}

// Round 11
// 61.033 us; speedup vs baseline: 1.2909x; 1.0154x over previous
//
#include <hip/hip_runtime.h>
#include <stddef.h>

#define CIN  128
#define COUT 128
#define KK   27
#define CAP  256     // pair capacity per (k, 2048-row superblock); mean 49, ~30 sigma
#define EMAX 96      // entries per 64-row output tile; mean ~40, ~9 sigma

typedef short bf16x8 __attribute__((ext_vector_type(8)));
typedef float f32x4  __attribute__((ext_vector_type(4)));

__device__ __forceinline__ short f2bf(float f) {
    unsigned u = __float_as_uint(f);
    unsigned r = (u + 0x7fffu + ((u >> 16) & 1u)) >> 16;
    return (short)r;
}
__device__ __forceinline__ float bf2f(short s) {
    unsigned u = ((unsigned)(unsigned short)s) << 16;
    return __uint_as_float(u);
}

#define PACK_UNITS (KK * 4 * 8 * 64)          // 55296 B-fragment slots
#define PACKB ((PACK_UNITS + 255) / 256)      // 216 blocks

// ============================================================================
// K1 pack_W: W fp32 -> bf16 MFMA B-fragment order (own kernel: consumers read
// Wp and cross-block ordering within a launch is undefined).
//   Wp[(((k*4+ks)*8+nf)*64+lane)*8+j] = bf16(W[k][ks*32+(lane>>4)*8+j][nf*16+(lane&15)])
// ============================================================================
__global__ __launch_bounds__(256) void pack_W(
    const float* __restrict__ W, short* __restrict__ Wp)
{
    int fl = blockIdx.x * 256 + threadIdx.x;
    if (fl >= PACK_UNITS) return;
    int lane = fl & 63, nf = (fl >> 6) & 7, ks = (fl >> 9) & 3, k = fl >> 11;
    int col  = nf * 16 + (lane & 15);
    int krow = ks * 32 + (lane >> 4) * 8;
    bf16x8 v;
    #pragma unroll
    for (int j = 0; j < 8; ++j)
        v[j] = f2bf(W[((size_t)k * CIN + krow + j) * COUT + col]);
    *reinterpret_cast<bf16x8*>(Wp + (size_t)fl * 8) = v;
}

// ============================================================================
// K2 bucket_gemm, per (k, 2048-row superblock) bucket:
//   (a) ballot-prefix compaction of (n, src) -> LDS plds (n-sorted) AND a
//       COALESCED pos[k*N+n] write (partial row index or -1);
//   (b) LDS-staged gather GEMM per 64-row tile (XOR-swizzled Asub).
// Block-local only: no atomics. k==13 skipped (center handled in K3).
// ============================================================================
__global__ __launch_bounds__(256) void bucket_gemm(
    const short* __restrict__ Wp, const int* __restrict__ nbr,
    const float* __restrict__ feats, int N, int nsb,
    int* __restrict__ pos, short* __restrict__ partial)
{
    const int b = blockIdx.x;                  // bucket = k*nsb + sb
    const int k = b / nsb, sb = b - k * nsb;
    if (k == 13) return;

    __shared__ short Asub[64 * 128];
    __shared__ int2 plds[CAP];
    __shared__ int wtot[4];
    __shared__ int sbase, scap;

    const int wave = threadIdx.x >> 6, lane = threadIdx.x & 63;
    const int lrow = lane & 15, lhi = lane >> 4;

    // ---- (a) compaction + coalesced pos writes ----
    if (threadIdx.x == 0) sbase = 0;
    __syncthreads();
    const int* nk   = nbr + (size_t)k * N;
    int*       posk = pos + (size_t)k * N;
    for (int c = 0; c < 8; ++c) {
        int n = sb * 2048 + c * 256 + threadIdx.x;
        int src = (n < N) ? nk[n] : -1;
        bool valid = (src >= 0);
        unsigned long long m = __ballot(valid);
        if (lane == 0) wtot[wave] = __popcll(m);
        __syncthreads();
        int off = sbase;
        for (int w = 0; w < wave; ++w) off += wtot[w];
        off += __popcll(m & ((1ull << lane) - 1ull));
        bool kept = valid && (off < CAP);
        if (kept) plds[off] = make_int2(n, src);
        if (n < N) posk[n] = kept ? (b * CAP + off) : -1;
        __syncthreads();
        if (threadIdx.x == 0) sbase += wtot[0] + wtot[1] + wtot[2] + wtot[3];
        __syncthreads();
    }
    if (threadIdx.x == 0) scap = (sbase < CAP) ? sbase : CAP;
    __syncthreads();
    const int cnt = scap;
    if (cnt == 0) return;

    // B-fragments (Wp packed by K1; L2-hot 16B/lane)
    bf16x8 bfr[2][4];
    #pragma unroll
    for (int nf = 0; nf < 2; ++nf)
        #pragma unroll
        for (int ks = 0; ks < 4; ++ks)
            bfr[nf][ks] = *reinterpret_cast<const bf16x8*>(
                Wp + ((size_t)((k * 4 + ks) * 8 + wave * 2 + nf) * 64 + lane) * 8);

    // ---- (b) LDS-staged gather GEMM, per 64-row tile ----
    for (int t0 = 0; t0 < cnt; t0 += 64) {
        __syncthreads();                       // protect Asub from prev tile
        #pragma unroll
        for (int j = 0; j < 4; ++j) {
            int slot = threadIdx.x + 256 * j;  // 64 rows x 16 chunks
            int row = slot >> 4, cg = slot & 15;
            int srow = t0 + row;
            bf16x8 v = {0,0,0,0,0,0,0,0};
            if (srow < cnt) {
                int src = plds[srow].y;
                const float* fr = feats + (size_t)src * CIN + cg * 8;
                float4 x = *reinterpret_cast<const float4*>(fr);
                float4 y = *reinterpret_cast<const float4*>(fr + 4);
                v = bf16x8{ f2bf(x.x), f2bf(x.y), f2bf(x.z), f2bf(x.w),
                            f2bf(y.x), f2bf(y.y), f2bf(y.z), f2bf(y.w) };
            }
            int sw = cg ^ (row & 7);
            *reinterpret_cast<bf16x8*>(&Asub[row * 128 + sw * 8]) = v;
        }
        __syncthreads();

        f32x4 zero = {0.f, 0.f, 0.f, 0.f};
        f32x4 acc[4][2];
        #pragma unroll
        for (int mf = 0; mf < 4; ++mf) { acc[mf][0] = zero; acc[mf][1] = zero; }

        #pragma unroll
        for (int ks = 0; ks < 4; ++ks)
            #pragma unroll
            for (int mf = 0; mf < 4; ++mf) {
                int row = mf * 16 + lrow;
                int sw = (ks * 4 + lhi) ^ (lrow & 7);
                bf16x8 a = *reinterpret_cast<const bf16x8*>(&Asub[row * 128 + sw * 8]);
                acc[mf][0] = __builtin_amdgcn_mfma_f32_16x16x32_bf16(a, bfr[0][ks], acc[mf][0], 0, 0, 0);
                acc[mf][1] = __builtin_amdgcn_mfma_f32_16x16x32_bf16(a, bfr[1][ks], acc[mf][1], 0, 0, 0);
            }

        #pragma unroll
        for (int mf = 0; mf < 4; ++mf)
            #pragma unroll
            for (int j = 0; j < 4; ++j) {
                int slot = t0 + mf * 16 + lhi * 4 + j;
                if (slot >= cnt) continue;
                short* dst = partial + ((size_t)b * CAP + slot) * COUT + wave * 32 + lrow;
                dst[0]  = f2bf(acc[mf][0][j]);
                dst[16] = f2bf(acc[mf][1][j]);
            }
    }
}

// ============================================================================
// K3 center + reduce, per 64-row tile:
//  (a) wave-parallel list build from pos (coalesced + ballot compact);
//  (d) cooperative Pbuf staging issued early (hides under (b));
//  (b) center MFMA via LDS-staged A-tile (identity gather, XOR swizzle);
//  (s) STABLE 16-BUCKET SORT of entries by (mf,j)=(row>>4,row&3) via per-wave
//      ballots -> apply uses STATIC accumulator indices (no if-converted
//      16-way select chains: was ~64 VALU/entry, now ~8);
//  (e) bucketed apply, batch-4 LDS reads;
//  (f) single out write from registers. No atomics.
// ============================================================================
__global__ __launch_bounds__(256) void center_reduce(
    const float* __restrict__ feats, const short* __restrict__ Wp13,
    const int* __restrict__ pos, const short* __restrict__ partial,
    float* __restrict__ out, int N)
{
    __shared__ short Asub[64 * 128];
    __shared__ short Pbuf[EMAX][136];
    __shared__ short erowL[EMAX];
    __shared__ int   eidxL[EMAX];
    __shared__ int   spacked[EMAX];
    __shared__ int   kcnt[KK], koff[KK];
    __shared__ int   w0cnt[16], w1cnt[16], boff16[16], bcnt16[16];
    __shared__ int   eTotS;

    const int tile0 = blockIdx.x * 64;
    const int t = threadIdx.x;
    const int wave = t >> 6, lane = t & 63;
    const int lrow = lane & 15, lhi = lane >> 4;

    // ---- (a) list build from pos ----
    int myv[7], mypfx[7];
    #pragma unroll
    for (int rd = 0; rd < 7; ++rd) {
        int k = rd * 4 + wave;
        int v = -1;
        if (k < KK && k != 13 && tile0 + lane < N)
            v = pos[(size_t)k * N + tile0 + lane];
        bool valid = (v >= 0);
        unsigned long long m = __ballot(valid);
        myv[rd] = v;
        mypfx[rd] = __popcll(m & ((1ull << lane) - 1ull));
        if (k < KK && lane == 0) kcnt[k] = __popcll(m);
    }
    __syncthreads();
    if (t == 0) {
        int a = 0;
        for (int k = 0; k < KK; ++k) { koff[k] = a; a += kcnt[k]; }
        eTotS = (a < EMAX) ? a : EMAX;
    }
    __syncthreads();
    #pragma unroll
    for (int rd = 0; rd < 7; ++rd) {
        int k = rd * 4 + wave;
        if (k < KK && myv[rd] >= 0) {
            int s = koff[k] + mypfx[rd];
            if (s < EMAX) { erowL[s] = (short)lane; eidxL[s] = myv[rd]; }
        }
    }
    __syncthreads();
    const int eTot = eTotS;

    // ---- (d) Pbuf staging issued early: latency hides under (b) ----
    for (int e = t >> 4; e < eTot; e += 16) {
        int sub = t & 15;
        *reinterpret_cast<bf16x8*>(&Pbuf[e][sub * 8]) =
            *reinterpret_cast<const bf16x8*>(partial + (size_t)eidxL[e] * COUT + sub * 8);
    }

    // ---- (s) stable 16-bucket counting sort by (mf,j); k-order preserved ----
    // entries live in waves 0,1 only (eTot <= 96 < 128)
    {
        int myb = -1;
        if (t < eTot) { int rr = erowL[t]; myb = ((rr >> 4) << 2) | (rr & 3); }
        int rank = 0;
        #pragma unroll
        for (int bb = 0; bb < 16; ++bb) {
            unsigned long long m = __ballot(myb == bb);
            if (lane == 0) {
                if (wave == 0) w0cnt[bb] = __popcll(m);
                else if (wave == 1) w1cnt[bb] = __popcll(m);
            }
            if (myb == bb) rank = __popcll(m & ((1ull << lane) - 1ull));
        }
        __syncthreads();
        if (t < 16) bcnt16[t] = w0cnt[t] + w1cnt[t];
        __syncthreads();
        if (t == 0) {
            int a = 0;
            for (int g = 0; g < 16; ++g) { boff16[g] = a; a += bcnt16[g]; }
        }
        __syncthreads();
        if (myb >= 0) {
            int r2 = rank + (wave == 1 ? w0cnt[myb] : 0);
            spacked[boff16[myb] + r2] = (t << 8) | (int)erowL[t];
        }
    }

    // ---- (b) center A-tile staging (identity gather, coalesced) ----
    #pragma unroll
    for (int j = 0; j < 4; ++j) {
        int slot = t + 256 * j;
        int row = slot >> 4, cg = slot & 15;
        int r = tile0 + row;
        bf16x8 v = {0,0,0,0,0,0,0,0};
        if (r < N) {
            const float* fr = feats + (size_t)r * CIN + cg * 8;
            float4 x = *reinterpret_cast<const float4*>(fr);
            float4 y = *reinterpret_cast<const float4*>(fr + 4);
            v = bf16x8{ f2bf(x.x), f2bf(x.y), f2bf(x.z), f2bf(x.w),
                        f2bf(y.x), f2bf(y.y), f2bf(y.z), f2bf(y.w) };
        }
        int sw = cg ^ (row & 7);
        *reinterpret_cast<bf16x8*>(&Asub[row * 128 + sw * 8]) = v;
    }

    bf16x8 bfr[2][4];
    #pragma unroll
    for (int nf = 0; nf < 2; ++nf)
        #pragma unroll
        for (int ks = 0; ks < 4; ++ks)
            bfr[nf][ks] = *reinterpret_cast<const bf16x8*>(
                Wp13 + ((size_t)(ks * 8 + wave * 2 + nf) * 64 + lane) * 8);

    __syncthreads();   // Asub + Pbuf + sort complete

    f32x4 zero = {0.f, 0.f, 0.f, 0.f};
    f32x4 acc[4][2];
    #pragma unroll
    for (int mf = 0; mf < 4; ++mf) { acc[mf][0] = zero; acc[mf][1] = zero; }

    #pragma unroll
    for (int ks = 0; ks < 4; ++ks)
        #pragma unroll
        for (int mf = 0; mf < 4; ++mf) {
            int row = mf * 16 + lrow;
            int sw = (ks * 4 + lhi) ^ (lrow & 7);
            bf16x8 a = *reinterpret_cast<const bf16x8*>(&Asub[row * 128 + sw * 8]);
            acc[mf][0] = __builtin_amdgcn_mfma_f32_16x16x32_bf16(a, bfr[0][ks], acc[mf][0], 0, 0, 0);
            acc[mf][1] = __builtin_amdgcn_mfma_f32_16x16x32_bf16(a, bfr[1][ks], acc[mf][1], 0, 0, 0);
        }

    // ---- (e) bucketed apply: static acc indices, batch-4 reads ----
    #pragma unroll
    for (int mf = 0; mf < 4; ++mf)
        #pragma unroll
        for (int j = 0; j < 4; ++j) {
            const int g = mf * 4 + j;
            const int s0 = boff16[g], c = bcnt16[g];
            for (int i0 = 0; i0 < c; i0 += 4) {
                int sp[4]; float q0[4], q1[4];
                #pragma unroll
                for (int u = 0; u < 4; ++u) {
                    int i = i0 + u;
                    sp[u] = (i < c) ? spacked[s0 + i] : -1;
                }
                #pragma unroll
                for (int u = 0; u < 4; ++u) {
                    if (sp[u] >= 0) {
                        int e = sp[u] >> 8;
                        q0[u] = bf2f(Pbuf[e][wave * 32 + lrow]);
                        q1[u] = bf2f(Pbuf[e][wave * 32 + 16 + lrow]);
                    } else { q0[u] = 0.f; q1[u] = 0.f; }
                }
                #pragma unroll
                for (int u = 0; u < 4; ++u) {
                    int rr = sp[u] & 255;
                    bool act = (sp[u] >= 0) && (lhi == ((rr >> 2) & 3));
                    acc[mf][0][j] += act ? q0[u] : 0.f;
                    acc[mf][1][j] += act ? q1[u] : 0.f;
                }
            }
        }

    // ---- (f) store out from registers ----
    #pragma unroll
    for (int mf = 0; mf < 4; ++mf)
        #pragma unroll
        for (int nf = 0; nf < 2; ++nf)
            #pragma unroll
            for (int j = 0; j < 4; ++j) {
                int r = tile0 + mf * 16 + lhi * 4 + j;
                if (r < N)
                    out[(size_t)r * COUT + wave * 32 + nf * 16 + lrow] = acc[mf][nf][j];
            }
}

// ============================================================================
// Fallback (ws too small): one block per voxel, fp32.
// ============================================================================
__global__ __launch_bounds__(128) void naive_spconv(
    const float* __restrict__ feats, const float* __restrict__ Wbase,
    const int* __restrict__ nbr, float* __restrict__ out, int N)
{
    int n  = blockIdx.x;
    int co = threadIdx.x;
    __shared__ float frow[CIN];
    float acc = 0.f;
    for (int k = 0; k < KK; ++k) {
        int src = nbr[(size_t)k * N + n];
        if (src < 0) continue;
        __syncthreads();
        frow[co] = feats[(size_t)src * CIN + co];
        __syncthreads();
        const float* Wk = Wbase + (size_t)k * CIN * COUT;
        #pragma unroll 8
        for (int ci = 0; ci < CIN; ++ci)
            acc = fmaf(frow[ci], Wk[ci * COUT + co], acc);
    }
    out[(size_t)n * COUT + co] = acc;
}

extern "C" void kernel_launch(void* const* d_in, const int* in_sizes, int n_in,
                              void* d_out, int out_size, void* d_ws, size_t ws_size,
                              hipStream_t stream) {
    const float* feats = (const float*)d_in[0];
    const float* Wb    = (const float*)d_in[1];
    const int*   nbr   = (const int*)d_in[2];
    float* out = (float*)d_out;
    const int N = in_sizes[0] / CIN;
    const int nsb = (N + 2047) >> 11;            // 2048-row superblocks
    const int nbk = KK * nsb;                    // buckets

    // ws: Wp bf16 27*16384 | pos int 27*N | partial bf16 nbk*CAP*128
    size_t off_wp   = 0;
    size_t off_pos  = ((size_t)PACK_UNITS * 8 * 2 + 255) & ~(size_t)255;
    size_t off_part = (off_pos + (size_t)KK * N * 4 + 255) & ~(size_t)255;
    size_t need = off_part + (size_t)nbk * CAP * COUT * 2;

    if (ws_size >= need) {
        short* wp   = (short*)((char*)d_ws + off_wp);
        int*   pos  = (int*)((char*)d_ws + off_pos);
        short* part = (short*)((char*)d_ws + off_part);

        pack_W<<<PACKB, 256, 0, stream>>>(Wb, wp);
        bucket_gemm<<<nbk, 256, 0, stream>>>(wp, nbr, feats, N, nsb, pos, part);
        center_reduce<<<(N + 63) / 64, 256, 0, stream>>>(
            feats, wp + (size_t)13 * 16384, pos, part, out, N);
    } else {
        naive_spconv<<<N, 128, 0, stream>>>(feats, Wb, nbr, out, N);
    }
}

// Round 12
// 50.960 us; speedup vs baseline: 1.5461x; 1.1977x over previous
//
#include <hip/hip_runtime.h>
#include <stddef.h>

#define CIN  128
#define COUT 128
#define KK   27
#define CAP  256     // pair capacity per (k, 2048-row superblock); mean 49, ~30 sigma
#define EMAX 96      // entries per 64-row output tile; mean ~40, ~9 sigma

typedef short bf16x8 __attribute__((ext_vector_type(8)));
typedef float f32x4  __attribute__((ext_vector_type(4)));

__device__ __forceinline__ short f2bf(float f) {
    unsigned u = __float_as_uint(f);
    unsigned r = (u + 0x7fffu + ((u >> 16) & 1u)) >> 16;
    return (short)r;
}
__device__ __forceinline__ float bf2f(short s) {
    unsigned u = ((unsigned)(unsigned short)s) << 16;
    return __uint_as_float(u);
}

#define PACK_UNITS (KK * 4 * 8 * 64)          // 55296 B-fragment slots
#define PACKB ((PACK_UNITS + 255) / 256)      // 216 blocks

// ============================================================================
// K1 pack_W: W fp32 -> bf16 MFMA B-fragment order (own kernel: consumers read
// Wp and cross-block ordering within a launch is undefined).
// ============================================================================
__global__ __launch_bounds__(256) void pack_W(
    const float* __restrict__ W, short* __restrict__ Wp)
{
    int fl = blockIdx.x * 256 + threadIdx.x;
    if (fl >= PACK_UNITS) return;
    int lane = fl & 63, nf = (fl >> 6) & 7, ks = (fl >> 9) & 3, k = fl >> 11;
    int col  = nf * 16 + (lane & 15);
    int krow = ks * 32 + (lane >> 4) * 8;
    bf16x8 v;
    #pragma unroll
    for (int j = 0; j < 8; ++j)
        v[j] = f2bf(W[((size_t)k * CIN + krow + j) * COUT + col]);
    *reinterpret_cast<bf16x8*>(Wp + (size_t)fl * 8) = v;
}

// ============================================================================
// K2 bucket_gemm, per (k, 2048-row superblock) bucket:
//   (a) ballot-prefix compaction -> LDS plds + coalesced pos[k*N+n] writes;
//   (b) LDS-staged gather GEMM per 64-row tile -> bf16 partial rows.
// ~18KB LDS -> high occupancy. k==13 skipped (center is identity).
// ============================================================================
__global__ __launch_bounds__(256) void bucket_gemm(
    const short* __restrict__ Wp, const int* __restrict__ nbr,
    const float* __restrict__ feats, int N, int nsb,
    int* __restrict__ pos, short* __restrict__ partial)
{
    const int b = blockIdx.x;                  // bucket = k*nsb + sb
    const int k = b / nsb, sb = b - k * nsb;
    if (k == 13) return;

    __shared__ short Asub[64 * 128];
    __shared__ int2 plds[CAP];
    __shared__ int wtot[4];
    __shared__ int sbase, scap;

    const int wave = threadIdx.x >> 6, lane = threadIdx.x & 63;
    const int lrow = lane & 15, lhi = lane >> 4;

    // ---- (a) compaction + coalesced pos writes ----
    if (threadIdx.x == 0) sbase = 0;
    __syncthreads();
    const int* nk   = nbr + (size_t)k * N;
    int*       posk = pos + (size_t)k * N;
    for (int c = 0; c < 8; ++c) {
        int n = sb * 2048 + c * 256 + threadIdx.x;
        int src = (n < N) ? nk[n] : -1;
        bool valid = (src >= 0);
        unsigned long long m = __ballot(valid);
        if (lane == 0) wtot[wave] = __popcll(m);
        __syncthreads();
        int off = sbase;
        for (int w = 0; w < wave; ++w) off += wtot[w];
        off += __popcll(m & ((1ull << lane) - 1ull));
        bool kept = valid && (off < CAP);
        if (kept) plds[off] = make_int2(n, src);
        if (n < N) posk[n] = kept ? (b * CAP + off) : -1;
        __syncthreads();
        if (threadIdx.x == 0) sbase += wtot[0] + wtot[1] + wtot[2] + wtot[3];
        __syncthreads();
    }
    if (threadIdx.x == 0) scap = (sbase < CAP) ? sbase : CAP;
    __syncthreads();
    const int cnt = scap;
    if (cnt == 0) return;

    bf16x8 bfr[2][4];
    #pragma unroll
    for (int nf = 0; nf < 2; ++nf)
        #pragma unroll
        for (int ks = 0; ks < 4; ++ks)
            bfr[nf][ks] = *reinterpret_cast<const bf16x8*>(
                Wp + ((size_t)((k * 4 + ks) * 8 + wave * 2 + nf) * 64 + lane) * 8);

    // ---- (b) LDS-staged gather GEMM, per 64-row tile ----
    for (int t0 = 0; t0 < cnt; t0 += 64) {
        __syncthreads();
        #pragma unroll
        for (int j = 0; j < 4; ++j) {
            int slot = threadIdx.x + 256 * j;
            int row = slot >> 4, cg = slot & 15;
            int srow = t0 + row;
            bf16x8 v = {0,0,0,0,0,0,0,0};
            if (srow < cnt) {
                int src = plds[srow].y;
                const float* fr = feats + (size_t)src * CIN + cg * 8;
                float4 x = *reinterpret_cast<const float4*>(fr);
                float4 y = *reinterpret_cast<const float4*>(fr + 4);
                v = bf16x8{ f2bf(x.x), f2bf(x.y), f2bf(x.z), f2bf(x.w),
                            f2bf(y.x), f2bf(y.y), f2bf(y.z), f2bf(y.w) };
            }
            int sw = cg ^ (row & 7);
            *reinterpret_cast<bf16x8*>(&Asub[row * 128 + sw * 8]) = v;
        }
        __syncthreads();

        f32x4 zero = {0.f, 0.f, 0.f, 0.f};
        f32x4 acc[4][2];
        #pragma unroll
        for (int mf = 0; mf < 4; ++mf) { acc[mf][0] = zero; acc[mf][1] = zero; }

        #pragma unroll
        for (int ks = 0; ks < 4; ++ks)
            #pragma unroll
            for (int mf = 0; mf < 4; ++mf) {
                int row = mf * 16 + lrow;
                int sw = (ks * 4 + lhi) ^ (lrow & 7);
                bf16x8 a = *reinterpret_cast<const bf16x8*>(&Asub[row * 128 + sw * 8]);
                acc[mf][0] = __builtin_amdgcn_mfma_f32_16x16x32_bf16(a, bfr[0][ks], acc[mf][0], 0, 0, 0);
                acc[mf][1] = __builtin_amdgcn_mfma_f32_16x16x32_bf16(a, bfr[1][ks], acc[mf][1], 0, 0, 0);
            }

        #pragma unroll
        for (int mf = 0; mf < 4; ++mf)
            #pragma unroll
            for (int j = 0; j < 4; ++j) {
                int slot = t0 + mf * 16 + lhi * 4 + j;
                if (slot >= cnt) continue;
                short* dst = partial + ((size_t)b * CAP + slot) * COUT + wave * 32 + lrow;
                dst[0]  = f2bf(acc[mf][0][j]);
                dst[16] = f2bf(acc[mf][1][j]);
            }
    }
}

// ============================================================================
// K3a center_gemm: pure streaming identity-gather MFMA (nbr[13][n]==n),
// 64-row tiles, LDS = 16KB Asub only -> ~8 blocks/CU. Writes all of out.
// ============================================================================
__global__ __launch_bounds__(256) void center_gemm(
    const float* __restrict__ feats, const short* __restrict__ Wp13,
    float* __restrict__ out, int N)
{
    __shared__ short Asub[64 * 128];
    const int tile0 = blockIdx.x * 64;
    const int t = threadIdx.x;
    const int wave = t >> 6, lane = t & 63;
    const int lrow = lane & 15, lhi = lane >> 4;

    #pragma unroll
    for (int j = 0; j < 4; ++j) {
        int slot = t + 256 * j;
        int row = slot >> 4, cg = slot & 15;
        int r = tile0 + row;
        bf16x8 v = {0,0,0,0,0,0,0,0};
        if (r < N) {
            const float* fr = feats + (size_t)r * CIN + cg * 8;
            float4 x = *reinterpret_cast<const float4*>(fr);
            float4 y = *reinterpret_cast<const float4*>(fr + 4);
            v = bf16x8{ f2bf(x.x), f2bf(x.y), f2bf(x.z), f2bf(x.w),
                        f2bf(y.x), f2bf(y.y), f2bf(y.z), f2bf(y.w) };
        }
        int sw = cg ^ (row & 7);
        *reinterpret_cast<bf16x8*>(&Asub[row * 128 + sw * 8]) = v;
    }

    bf16x8 bfr[2][4];
    #pragma unroll
    for (int nf = 0; nf < 2; ++nf)
        #pragma unroll
        for (int ks = 0; ks < 4; ++ks)
            bfr[nf][ks] = *reinterpret_cast<const bf16x8*>(
                Wp13 + ((size_t)(ks * 8 + wave * 2 + nf) * 64 + lane) * 8);

    __syncthreads();

    f32x4 zero = {0.f, 0.f, 0.f, 0.f};
    f32x4 acc[4][2];
    #pragma unroll
    for (int mf = 0; mf < 4; ++mf) { acc[mf][0] = zero; acc[mf][1] = zero; }

    #pragma unroll
    for (int ks = 0; ks < 4; ++ks)
        #pragma unroll
        for (int mf = 0; mf < 4; ++mf) {
            int row = mf * 16 + lrow;
            int sw = (ks * 4 + lhi) ^ (lrow & 7);
            bf16x8 a = *reinterpret_cast<const bf16x8*>(&Asub[row * 128 + sw * 8]);
            acc[mf][0] = __builtin_amdgcn_mfma_f32_16x16x32_bf16(a, bfr[0][ks], acc[mf][0], 0, 0, 0);
            acc[mf][1] = __builtin_amdgcn_mfma_f32_16x16x32_bf16(a, bfr[1][ks], acc[mf][1], 0, 0, 0);
        }

    #pragma unroll
    for (int mf = 0; mf < 4; ++mf)
        #pragma unroll
        for (int nf = 0; nf < 2; ++nf)
            #pragma unroll
            for (int j = 0; j < 4; ++j) {
                int r = tile0 + mf * 16 + lhi * 4 + j;
                if (r < N)
                    out[(size_t)r * COUT + wave * 32 + nf * 16 + lrow] = acc[mf][nf][j];
            }
}

// ============================================================================
// K3b scatter_add, per 64-row tile:
//  (a) wave-parallel list build from pos (coalesced + ballot compact; k-major);
//  (d) cooperative Pbuf staging (16 thr x 16B per entry row, vectorized);
//  (e) 4 threads per out row scan the entry list (erow is an LDS broadcast;
//      waves with no matching row branch around via execz); matches add 32
//      cols from Pbuf into registers; k-major order -> deterministic;
//  (f) rows with >=1 entry do one read-add-write of out (center already there).
// LDS ~27KB, no Asub -> ~5 blocks/CU.
// ============================================================================
__global__ __launch_bounds__(256) void scatter_add(
    const int* __restrict__ pos, const short* __restrict__ partial,
    float* __restrict__ out, int N)
{
    __shared__ short Pbuf[EMAX][136];
    __shared__ short erowL[EMAX];
    __shared__ int   eidxL[EMAX];
    __shared__ int   kcnt[KK], koff[KK];
    __shared__ int   eTotS;

    const int tile0 = blockIdx.x * 64;
    const int t = threadIdx.x;
    const int wave = t >> 6, lane = t & 63;

    // ---- (a) list build from pos ----
    int myv[7], mypfx[7];
    #pragma unroll
    for (int rd = 0; rd < 7; ++rd) {
        int k = rd * 4 + wave;
        int v = -1;
        if (k < KK && k != 13 && tile0 + lane < N)
            v = pos[(size_t)k * N + tile0 + lane];
        bool valid = (v >= 0);
        unsigned long long m = __ballot(valid);
        myv[rd] = v;
        mypfx[rd] = __popcll(m & ((1ull << lane) - 1ull));
        if (k < KK && lane == 0) kcnt[k] = __popcll(m);
    }
    __syncthreads();
    if (t == 0) {
        int a = 0;
        for (int k = 0; k < KK; ++k) { koff[k] = a; a += kcnt[k]; }
        eTotS = (a < EMAX) ? a : EMAX;
    }
    __syncthreads();
    #pragma unroll
    for (int rd = 0; rd < 7; ++rd) {
        int k = rd * 4 + wave;
        if (k < KK && myv[rd] >= 0) {
            int s = koff[k] + mypfx[rd];
            if (s < EMAX) { erowL[s] = (short)lane; eidxL[s] = myv[rd]; }
        }
    }
    __syncthreads();
    const int eTot = eTotS;
    if (eTot == 0) return;

    // ---- (d) cooperative Pbuf staging ----
    for (int e = t >> 4; e < eTot; e += 16) {
        int sub = t & 15;
        *reinterpret_cast<bf16x8*>(&Pbuf[e][sub * 8]) =
            *reinterpret_cast<const bf16x8*>(partial + (size_t)eidxL[e] * COUT + sub * 8);
    }
    __syncthreads();

    // ---- (e) per-row predicated scan, register accumulate ----
    const int r = t >> 2, q = t & 3;           // 4 threads/row, 32 cols each
    float acc[32];
    #pragma unroll
    for (int i = 0; i < 32; ++i) acc[i] = 0.f;
    bool any = false;

    #pragma unroll 1
    for (int e = 0; e < eTot; ++e) {
        if ((int)erowL[e] != r) continue;      // execz skip for 3 of 4 waves
        any = true;
        #pragma unroll
        for (int v8 = 0; v8 < 4; ++v8) {
            bf16x8 p = *reinterpret_cast<const bf16x8*>(&Pbuf[e][q * 32 + v8 * 8]);
            #pragma unroll
            for (int j = 0; j < 8; ++j) acc[v8 * 8 + j] += bf2f(p[j]);
        }
    }

    // ---- (f) RMW touched out rows ----
    if (any && tile0 + r < N) {
        float* dst = out + (size_t)(tile0 + r) * COUT + q * 32;
        #pragma unroll
        for (int v4 = 0; v4 < 8; ++v4) {
            float4 o = *reinterpret_cast<float4*>(dst + v4 * 4);
            o.x += acc[v4 * 4 + 0]; o.y += acc[v4 * 4 + 1];
            o.z += acc[v4 * 4 + 2]; o.w += acc[v4 * 4 + 3];
            *reinterpret_cast<float4*>(dst + v4 * 4) = o;
        }
    }
}

// ============================================================================
// Fallback (ws too small): one block per voxel, fp32.
// ============================================================================
__global__ __launch_bounds__(128) void naive_spconv(
    const float* __restrict__ feats, const float* __restrict__ Wbase,
    const int* __restrict__ nbr, float* __restrict__ out, int N)
{
    int n  = blockIdx.x;
    int co = threadIdx.x;
    __shared__ float frow[CIN];
    float acc = 0.f;
    for (int k = 0; k < KK; ++k) {
        int src = nbr[(size_t)k * N + n];
        if (src < 0) continue;
        __syncthreads();
        frow[co] = feats[(size_t)src * CIN + co];
        __syncthreads();
        const float* Wk = Wbase + (size_t)k * CIN * COUT;
        #pragma unroll 8
        for (int ci = 0; ci < CIN; ++ci)
            acc = fmaf(frow[ci], Wk[ci * COUT + co], acc);
    }
    out[(size_t)n * COUT + co] = acc;
}

extern "C" void kernel_launch(void* const* d_in, const int* in_sizes, int n_in,
                              void* d_out, int out_size, void* d_ws, size_t ws_size,
                              hipStream_t stream) {
    const float* feats = (const float*)d_in[0];
    const float* Wb    = (const float*)d_in[1];
    const int*   nbr   = (const int*)d_in[2];
    float* out = (float*)d_out;
    const int N = in_sizes[0] / CIN;
    const int nsb = (N + 2047) >> 11;            // 2048-row superblocks
    const int nbk = KK * nsb;                    // buckets

    // ws: Wp bf16 27*16384 | pos int 27*N | partial bf16 nbk*CAP*128
    size_t off_wp   = 0;
    size_t off_pos  = ((size_t)PACK_UNITS * 8 * 2 + 255) & ~(size_t)255;
    size_t off_part = (off_pos + (size_t)KK * N * 4 + 255) & ~(size_t)255;
    size_t need = off_part + (size_t)nbk * CAP * COUT * 2;

    if (ws_size >= need) {
        short* wp   = (short*)((char*)d_ws + off_wp);
        int*   pos  = (int*)((char*)d_ws + off_pos);
        short* part = (short*)((char*)d_ws + off_part);

        pack_W<<<PACKB, 256, 0, stream>>>(Wb, wp);
        bucket_gemm<<<nbk, 256, 0, stream>>>(wp, nbr, feats, N, nsb, pos, part);
        center_gemm<<<(N + 63) / 64, 256, 0, stream>>>(
            feats, wp + (size_t)13 * 16384, out, N);
        scatter_add<<<(N + 63) / 64, 256, 0, stream>>>(pos, part, out, N);
    } else {
        naive_spconv<<<N, 128, 0, stream>>>(feats, Wb, nbr, out, N);
    }
}

// Round 13
// 45.237 us; speedup vs baseline: 1.7416x; 1.1265x over previous
//
#include <hip/hip_runtime.h>
#include <stddef.h>

#define CIN  128
#define COUT 128
#define KK   27
#define CAP  256     // partial-row stride per bucket
#define CMAX 255     // max entries per bucket (255 = pos sentinel); mean 49, ~29 sigma
#define EMAX 96      // entries per 64-row output tile; mean ~40, ~9 sigma

typedef short bf16x8 __attribute__((ext_vector_type(8)));
typedef float f32x4  __attribute__((ext_vector_type(4)));

__device__ __forceinline__ short f2bf(float f) {
    unsigned u = __float_as_uint(f);
    unsigned r = (u + 0x7fffu + ((u >> 16) & 1u)) >> 16;
    return (short)r;
}
__device__ __forceinline__ float bf2f(short s) {
    unsigned u = ((unsigned)(unsigned short)s) << 16;
    return __uint_as_float(u);
}

#define PACK_UNITS (KK * 4 * 8 * 64)          // 55296 B-fragment slots
#define PACKB ((PACK_UNITS + 255) / 256)      // 216 blocks

// ============================================================================
// K1 pack_W: W fp32 -> bf16 MFMA B-fragment order (own kernel: consumers in
// the NEXT launch read Wp; cross-block ordering within a launch is undefined).
// ============================================================================
__global__ __launch_bounds__(256) void pack_W(
    const float* __restrict__ W, short* __restrict__ Wp)
{
    int fl = blockIdx.x * 256 + threadIdx.x;
    if (fl >= PACK_UNITS) return;
    int lane = fl & 63, nf = (fl >> 6) & 7, ks = (fl >> 9) & 3, k = fl >> 11;
    int col  = nf * 16 + (lane & 15);
    int krow = ks * 32 + (lane >> 4) * 8;
    bf16x8 v;
    #pragma unroll
    for (int j = 0; j < 8; ++j)
        v[j] = f2bf(W[((size_t)k * CIN + krow + j) * COUT + col]);
    *reinterpret_cast<bf16x8*>(Wp + (size_t)fl * 8) = v;
}

// ============================================================================
// K2 fused_gemm:
//  blocks [0, nbk):    bucket path — per (k, 2048-row superblock):
//    (a) prefetched ballot-prefix compaction -> LDS plds + uint8 pos slots;
//    (b) LDS-staged gather GEMM per 64-row tile -> bf16 partial rows.
//  blocks [nbk, ...):  center path — streaming identity-gather MFMA
//    (nbr[13][n]==n by construction), writes all of out.
//  The two paths share no produced data (pos/partial vs out; Wp is read-only,
//  produced by the previous launch) -> safe to co-launch.
// ============================================================================
__global__ __launch_bounds__(256) void fused_gemm(
    const short* __restrict__ Wp, const int* __restrict__ nbr,
    const float* __restrict__ feats, int N, int nsb, int nbk,
    unsigned char* __restrict__ pos, short* __restrict__ partial,
    float* __restrict__ out)
{
    __shared__ short Asub[64 * 128];
    const int t = threadIdx.x;
    const int wave = t >> 6, lane = t & 63;
    const int lrow = lane & 15, lhi = lane >> 4;

    if ((int)blockIdx.x >= nbk) {
        // ---------------------- center path ----------------------
        const int tile0 = ((int)blockIdx.x - nbk) * 64;
        const short* Wp13 = Wp + (size_t)13 * 16384;

        #pragma unroll
        for (int j = 0; j < 4; ++j) {
            int slot = t + 256 * j;
            int row = slot >> 4, cg = slot & 15;
            int r = tile0 + row;
            bf16x8 v = {0,0,0,0,0,0,0,0};
            if (r < N) {
                const float* fr = feats + (size_t)r * CIN + cg * 8;
                float4 x = *reinterpret_cast<const float4*>(fr);
                float4 y = *reinterpret_cast<const float4*>(fr + 4);
                v = bf16x8{ f2bf(x.x), f2bf(x.y), f2bf(x.z), f2bf(x.w),
                            f2bf(y.x), f2bf(y.y), f2bf(y.z), f2bf(y.w) };
            }
            int sw = cg ^ (row & 7);
            *reinterpret_cast<bf16x8*>(&Asub[row * 128 + sw * 8]) = v;
        }

        bf16x8 bfr[2][4];
        #pragma unroll
        for (int nf = 0; nf < 2; ++nf)
            #pragma unroll
            for (int ks = 0; ks < 4; ++ks)
                bfr[nf][ks] = *reinterpret_cast<const bf16x8*>(
                    Wp13 + ((size_t)(ks * 8 + wave * 2 + nf) * 64 + lane) * 8);

        __syncthreads();

        f32x4 zero = {0.f, 0.f, 0.f, 0.f};
        f32x4 acc[4][2];
        #pragma unroll
        for (int mf = 0; mf < 4; ++mf) { acc[mf][0] = zero; acc[mf][1] = zero; }

        #pragma unroll
        for (int ks = 0; ks < 4; ++ks)
            #pragma unroll
            for (int mf = 0; mf < 4; ++mf) {
                int row = mf * 16 + lrow;
                int sw = (ks * 4 + lhi) ^ (lrow & 7);
                bf16x8 a = *reinterpret_cast<const bf16x8*>(&Asub[row * 128 + sw * 8]);
                acc[mf][0] = __builtin_amdgcn_mfma_f32_16x16x32_bf16(a, bfr[0][ks], acc[mf][0], 0, 0, 0);
                acc[mf][1] = __builtin_amdgcn_mfma_f32_16x16x32_bf16(a, bfr[1][ks], acc[mf][1], 0, 0, 0);
            }

        #pragma unroll
        for (int mf = 0; mf < 4; ++mf)
            #pragma unroll
            for (int nf = 0; nf < 2; ++nf)
                #pragma unroll
                for (int j = 0; j < 4; ++j) {
                    int r = tile0 + mf * 16 + lhi * 4 + j;
                    if (r < N)
                        out[(size_t)r * COUT + wave * 32 + nf * 16 + lrow] = acc[mf][nf][j];
                }
        return;
    }

    // ------------------------ bucket path ------------------------
    const int b = blockIdx.x;                  // bucket = k*nsb + sb
    const int k = b / nsb, sb = b - k * nsb;
    if (k == 13) return;

    __shared__ int2 plds[CAP];
    __shared__ int wtot[4];
    __shared__ int sbase, scap;

    const int* nk = nbr + (size_t)k * N;
    unsigned char* posk = pos + (size_t)k * N;

    // prefetch all 8 rounds (independent coalesced loads, one latency)
    int nn[8], nsrc[8];
    #pragma unroll
    for (int c = 0; c < 8; ++c) {
        nn[c] = sb * 2048 + c * 256 + t;
        nsrc[c] = (nn[c] < N) ? nk[nn[c]] : -1;
    }

    // ---- (a) compaction + uint8 pos writes ----
    if (t == 0) sbase = 0;
    __syncthreads();
    #pragma unroll 1
    for (int c = 0; c < 8; ++c) {
        bool valid = (nsrc[c] >= 0);
        unsigned long long m = __ballot(valid);
        if (lane == 0) wtot[wave] = __popcll(m);
        __syncthreads();
        int off = sbase;
        for (int w = 0; w < wave; ++w) off += wtot[w];
        off += __popcll(m & ((1ull << lane) - 1ull));
        bool kept = valid && (off < CMAX);
        if (kept) plds[off] = make_int2(nn[c], nsrc[c]);
        if (nn[c] < N) posk[nn[c]] = kept ? (unsigned char)off : (unsigned char)255;
        __syncthreads();
        if (t == 0) sbase += wtot[0] + wtot[1] + wtot[2] + wtot[3];
        __syncthreads();
    }
    if (t == 0) scap = (sbase < CMAX) ? sbase : CMAX;
    __syncthreads();
    const int cnt = scap;
    if (cnt == 0) return;

    bf16x8 bfr[2][4];
    #pragma unroll
    for (int nf = 0; nf < 2; ++nf)
        #pragma unroll
        for (int ks = 0; ks < 4; ++ks)
            bfr[nf][ks] = *reinterpret_cast<const bf16x8*>(
                Wp + ((size_t)((k * 4 + ks) * 8 + wave * 2 + nf) * 64 + lane) * 8);

    // ---- (b) LDS-staged gather GEMM, per 64-row tile ----
    for (int t0 = 0; t0 < cnt; t0 += 64) {
        __syncthreads();
        #pragma unroll
        for (int j = 0; j < 4; ++j) {
            int slot = t + 256 * j;
            int row = slot >> 4, cg = slot & 15;
            int srow = t0 + row;
            bf16x8 v = {0,0,0,0,0,0,0,0};
            if (srow < cnt) {
                int src = plds[srow].y;
                const float* fr = feats + (size_t)src * CIN + cg * 8;
                float4 x = *reinterpret_cast<const float4*>(fr);
                float4 y = *reinterpret_cast<const float4*>(fr + 4);
                v = bf16x8{ f2bf(x.x), f2bf(x.y), f2bf(x.z), f2bf(x.w),
                            f2bf(y.x), f2bf(y.y), f2bf(y.z), f2bf(y.w) };
            }
            int sw = cg ^ (row & 7);
            *reinterpret_cast<bf16x8*>(&Asub[row * 128 + sw * 8]) = v;
        }
        __syncthreads();

        f32x4 zero = {0.f, 0.f, 0.f, 0.f};
        f32x4 acc[4][2];
        #pragma unroll
        for (int mf = 0; mf < 4; ++mf) { acc[mf][0] = zero; acc[mf][1] = zero; }

        #pragma unroll
        for (int ks = 0; ks < 4; ++ks)
            #pragma unroll
            for (int mf = 0; mf < 4; ++mf) {
                int row = mf * 16 + lrow;
                int sw = (ks * 4 + lhi) ^ (lrow & 7);
                bf16x8 a = *reinterpret_cast<const bf16x8*>(&Asub[row * 128 + sw * 8]);
                acc[mf][0] = __builtin_amdgcn_mfma_f32_16x16x32_bf16(a, bfr[0][ks], acc[mf][0], 0, 0, 0);
                acc[mf][1] = __builtin_amdgcn_mfma_f32_16x16x32_bf16(a, bfr[1][ks], acc[mf][1], 0, 0, 0);
            }

        #pragma unroll
        for (int mf = 0; mf < 4; ++mf)
            #pragma unroll
            for (int j = 0; j < 4; ++j) {
                int slot = t0 + mf * 16 + lhi * 4 + j;
                if (slot >= cnt) continue;
                short* dst = partial + ((size_t)b * CAP + slot) * COUT + wave * 32 + lrow;
                dst[0]  = f2bf(acc[mf][0][j]);
                dst[16] = f2bf(acc[mf][1][j]);
            }
    }
}

// ============================================================================
// K3 scatter_add, per 64-row tile:
//  (a) wave-parallel list build from uint8 pos (coalesced + ballot compact);
//  (d) cooperative Pbuf staging (16 thr x 16B per entry row, vectorized);
//  (e) 4 threads per out row scan the entry list (erow is an LDS broadcast;
//      waves with no matching row skip via execz); k-major -> deterministic;
//  (f) rows with >=1 entry do one read-add-write of out.
// ============================================================================
__global__ __launch_bounds__(256) void scatter_add(
    const unsigned char* __restrict__ pos, const short* __restrict__ partial,
    float* __restrict__ out, int N, int nsb)
{
    __shared__ short Pbuf[EMAX][136];
    __shared__ short erowL[EMAX];
    __shared__ int   eidxL[EMAX];
    __shared__ int   kcnt[KK], koff[KK];
    __shared__ int   eTotS;

    const int tile0 = blockIdx.x * 64;
    const int sbk = tile0 >> 11;               // superblock of this tile
    const int t = threadIdx.x;
    const int wave = t >> 6, lane = t & 63;

    // ---- (a) list build from pos ----
    int myv[7], mypfx[7];
    #pragma unroll
    for (int rd = 0; rd < 7; ++rd) {
        int k = rd * 4 + wave;
        int v = -1;
        if (k < KK && k != 13 && tile0 + lane < N) {
            unsigned char p = pos[(size_t)k * N + tile0 + lane];
            if (p != 255) v = (int)p;
        }
        bool valid = (v >= 0);
        unsigned long long m = __ballot(valid);
        myv[rd] = valid ? (((k * nsb + sbk) * CAP) + v) : -1;
        mypfx[rd] = __popcll(m & ((1ull << lane) - 1ull));
        if (k < KK && lane == 0) kcnt[k] = __popcll(m);
    }
    __syncthreads();
    if (t == 0) {
        int a = 0;
        for (int k = 0; k < KK; ++k) { koff[k] = a; a += kcnt[k]; }
        eTotS = (a < EMAX) ? a : EMAX;
    }
    __syncthreads();
    #pragma unroll
    for (int rd = 0; rd < 7; ++rd) {
        int k = rd * 4 + wave;
        if (k < KK && myv[rd] >= 0) {
            int s = koff[k] + mypfx[rd];
            if (s < EMAX) { erowL[s] = (short)lane; eidxL[s] = myv[rd]; }
        }
    }
    __syncthreads();
    const int eTot = eTotS;
    if (eTot == 0) return;

    // ---- (d) cooperative Pbuf staging ----
    for (int e = t >> 4; e < eTot; e += 16) {
        int sub = t & 15;
        *reinterpret_cast<bf16x8*>(&Pbuf[e][sub * 8]) =
            *reinterpret_cast<const bf16x8*>(partial + (size_t)eidxL[e] * COUT + sub * 8);
    }
    __syncthreads();

    // ---- (e) per-row predicated scan, register accumulate ----
    const int r = t >> 2, q = t & 3;           // 4 threads/row, 32 cols each
    float acc[32];
    #pragma unroll
    for (int i = 0; i < 32; ++i) acc[i] = 0.f;
    bool any = false;

    #pragma unroll 1
    for (int e = 0; e < eTot; ++e) {
        if ((int)erowL[e] != r) continue;      // execz skip
        any = true;
        #pragma unroll
        for (int v8 = 0; v8 < 4; ++v8) {
            bf16x8 p = *reinterpret_cast<const bf16x8*>(&Pbuf[e][q * 32 + v8 * 8]);
            #pragma unroll
            for (int j = 0; j < 8; ++j) acc[v8 * 8 + j] += bf2f(p[j]);
        }
    }

    // ---- (f) RMW touched out rows ----
    if (any && tile0 + r < N) {
        float* dst = out + (size_t)(tile0 + r) * COUT + q * 32;
        #pragma unroll
        for (int v4 = 0; v4 < 8; ++v4) {
            float4 o = *reinterpret_cast<float4*>(dst + v4 * 4);
            o.x += acc[v4 * 4 + 0]; o.y += acc[v4 * 4 + 1];
            o.z += acc[v4 * 4 + 2]; o.w += acc[v4 * 4 + 3];
            *reinterpret_cast<float4*>(dst + v4 * 4) = o;
        }
    }
}

// ============================================================================
// Fallback (ws too small): one block per voxel, fp32.
// ============================================================================
__global__ __launch_bounds__(128) void naive_spconv(
    const float* __restrict__ feats, const float* __restrict__ Wbase,
    const int* __restrict__ nbr, float* __restrict__ out, int N)
{
    int n  = blockIdx.x;
    int co = threadIdx.x;
    __shared__ float frow[CIN];
    float acc = 0.f;
    for (int k = 0; k < KK; ++k) {
        int src = nbr[(size_t)k * N + n];
        if (src < 0) continue;
        __syncthreads();
        frow[co] = feats[(size_t)src * CIN + co];
        __syncthreads();
        const float* Wk = Wbase + (size_t)k * CIN * COUT;
        #pragma unroll 8
        for (int ci = 0; ci < CIN; ++ci)
            acc = fmaf(frow[ci], Wk[ci * COUT + co], acc);
    }
    out[(size_t)n * COUT + co] = acc;
}

extern "C" void kernel_launch(void* const* d_in, const int* in_sizes, int n_in,
                              void* d_out, int out_size, void* d_ws, size_t ws_size,
                              hipStream_t stream) {
    const float* feats = (const float*)d_in[0];
    const float* Wb    = (const float*)d_in[1];
    const int*   nbr   = (const int*)d_in[2];
    float* out = (float*)d_out;
    const int N = in_sizes[0] / CIN;
    const int nsb = (N + 2047) >> 11;            // 2048-row superblocks
    const int nbk = KK * nsb;                    // buckets
    const int ctiles = (N + 63) / 64;

    // ws: Wp bf16 27*16384 | pos u8 27*N | partial bf16 nbk*CAP*128
    size_t off_wp   = 0;
    size_t off_pos  = ((size_t)PACK_UNITS * 8 * 2 + 255) & ~(size_t)255;
    size_t off_part = (off_pos + (size_t)KK * N + 255) & ~(size_t)255;
    size_t need = off_part + (size_t)nbk * CAP * COUT * 2;

    if (ws_size >= need) {
        short*         wp   = (short*)((char*)d_ws + off_wp);
        unsigned char* pos  = (unsigned char*)((char*)d_ws + off_pos);
        short*         part = (short*)((char*)d_ws + off_part);

        pack_W<<<PACKB, 256, 0, stream>>>(Wb, wp);
        fused_gemm<<<nbk + ctiles, 256, 0, stream>>>(wp, nbr, feats, N, nsb, nbk,
                                                     pos, part, out);
        scatter_add<<<ctiles, 256, 0, stream>>>(pos, part, out, N, nsb);
    } else {
        naive_spconv<<<N, 128, 0, stream>>>(feats, Wb, nbr, out, N);
    }
}

// Round 14
// 39.886 us; speedup vs baseline: 1.9753x; 1.1342x over previous
//
#include <hip/hip_runtime.h>
#include <stddef.h>

#define CIN  128
#define COUT 128
#define KK   27
#define CAP  256     // partial-row stride per bucket
#define CMAX 255     // max entries per bucket (255 = pos sentinel); mean 49, ~29 sigma
#define EMAX 96      // entries per 64-row output tile; mean ~40, ~9 sigma

typedef short bf16x8 __attribute__((ext_vector_type(8)));
typedef float f32x4  __attribute__((ext_vector_type(4)));

__device__ __forceinline__ short f2bf(float f) {
    unsigned u = __float_as_uint(f);
    unsigned r = (u + 0x7fffu + ((u >> 16) & 1u)) >> 16;
    return (short)r;
}
__device__ __forceinline__ float bf2f(short s) {
    unsigned u = ((unsigned)(unsigned short)s) << 16;
    return __uint_as_float(u);
}

#define PACK_UNITS (KK * 4 * 8 * 64)          // 55296 B-fragment slots
#define PACKB ((PACK_UNITS + 255) / 256)      // 216 blocks

// ============================================================================
// K1 pack_W: W fp32 -> bf16 MFMA B-fragment order (own kernel: consumers in
// the NEXT launch read Wp; cross-block ordering within a launch is undefined).
// ============================================================================
__global__ __launch_bounds__(256) void pack_W(
    const float* __restrict__ W, short* __restrict__ Wp)
{
    int fl = blockIdx.x * 256 + threadIdx.x;
    if (fl >= PACK_UNITS) return;
    int lane = fl & 63, nf = (fl >> 6) & 7, ks = (fl >> 9) & 3, k = fl >> 11;
    int col  = nf * 16 + (lane & 15);
    int krow = ks * 32 + (lane >> 4) * 8;
    bf16x8 v;
    #pragma unroll
    for (int j = 0; j < 8; ++j)
        v[j] = f2bf(W[((size_t)k * CIN + krow + j) * COUT + col]);
    *reinterpret_cast<bf16x8*>(Wp + (size_t)fl * 8) = v;
}

// ============================================================================
// K2 fused_gemm:
//  blocks [0, nbk):    bucket path — per (k, 2048-row superblock):
//    (a) 3-BARRIER compaction: prefetch 8 chunks, 8 barrier-free ballots,
//        32-count LDS scan by t0, then unconditional plds/pos writes;
//    (b) LDS-staged gather GEMM per 64-row tile -> bf16 partial rows.
//  blocks [nbk, ...):  center path — streaming identity-gather MFMA
//    (nbr[13][n]==n by construction), writes all of out.
//  Paths share no produced data (Wp read-only from prior launch) -> safe.
// ============================================================================
__global__ __launch_bounds__(256) void fused_gemm(
    const short* __restrict__ Wp, const int* __restrict__ nbr,
    const float* __restrict__ feats, int N, int nsb, int nbk,
    unsigned char* __restrict__ pos, short* __restrict__ partial,
    float* __restrict__ out)
{
    __shared__ short Asub[64 * 128];
    const int t = threadIdx.x;
    const int wave = t >> 6, lane = t & 63;
    const int lrow = lane & 15, lhi = lane >> 4;

    if ((int)blockIdx.x >= nbk) {
        // ---------------------- center path ----------------------
        const int tile0 = ((int)blockIdx.x - nbk) * 64;
        const short* Wp13 = Wp + (size_t)13 * 16384;

        #pragma unroll
        for (int j = 0; j < 4; ++j) {
            int slot = t + 256 * j;
            int row = slot >> 4, cg = slot & 15;
            int r = tile0 + row;
            bf16x8 v = {0,0,0,0,0,0,0,0};
            if (r < N) {
                const float* fr = feats + (size_t)r * CIN + cg * 8;
                float4 x = *reinterpret_cast<const float4*>(fr);
                float4 y = *reinterpret_cast<const float4*>(fr + 4);
                v = bf16x8{ f2bf(x.x), f2bf(x.y), f2bf(x.z), f2bf(x.w),
                            f2bf(y.x), f2bf(y.y), f2bf(y.z), f2bf(y.w) };
            }
            int sw = cg ^ (row & 7);
            *reinterpret_cast<bf16x8*>(&Asub[row * 128 + sw * 8]) = v;
        }

        bf16x8 bfr[2][4];
        #pragma unroll
        for (int nf = 0; nf < 2; ++nf)
            #pragma unroll
            for (int ks = 0; ks < 4; ++ks)
                bfr[nf][ks] = *reinterpret_cast<const bf16x8*>(
                    Wp13 + ((size_t)(ks * 8 + wave * 2 + nf) * 64 + lane) * 8);

        __syncthreads();

        f32x4 zero = {0.f, 0.f, 0.f, 0.f};
        f32x4 acc[4][2];
        #pragma unroll
        for (int mf = 0; mf < 4; ++mf) { acc[mf][0] = zero; acc[mf][1] = zero; }

        #pragma unroll
        for (int ks = 0; ks < 4; ++ks)
            #pragma unroll
            for (int mf = 0; mf < 4; ++mf) {
                int row = mf * 16 + lrow;
                int sw = (ks * 4 + lhi) ^ (lrow & 7);
                bf16x8 a = *reinterpret_cast<const bf16x8*>(&Asub[row * 128 + sw * 8]);
                acc[mf][0] = __builtin_amdgcn_mfma_f32_16x16x32_bf16(a, bfr[0][ks], acc[mf][0], 0, 0, 0);
                acc[mf][1] = __builtin_amdgcn_mfma_f32_16x16x32_bf16(a, bfr[1][ks], acc[mf][1], 0, 0, 0);
            }

        #pragma unroll
        for (int mf = 0; mf < 4; ++mf)
            #pragma unroll
            for (int nf = 0; nf < 2; ++nf)
                #pragma unroll
                for (int j = 0; j < 4; ++j) {
                    int r = tile0 + mf * 16 + lhi * 4 + j;
                    if (r < N)
                        out[(size_t)r * COUT + wave * 32 + nf * 16 + lrow] = acc[mf][nf][j];
                }
        return;
    }

    // ------------------------ bucket path ------------------------
    const int b = blockIdx.x;                  // bucket = k*nsb + sb
    const int k = b / nsb, sb = b - k * nsb;
    if (k == 13) return;

    __shared__ int2 plds[CAP];
    __shared__ int cw[32];                     // per-(chunk,wave) counts -> scan
    __shared__ int sbase, scap;

    const int* nk = nbr + (size_t)k * N;
    unsigned char* posk = pos + (size_t)k * N;

    // ---- (a) 3-barrier compaction ----
    // prefetch all 8 chunks (independent coalesced loads)
    int nsrc[8];
    #pragma unroll
    for (int c = 0; c < 8; ++c) {
        int n = sb * 2048 + c * 256 + t;
        nsrc[c] = (n < N) ? nk[n] : -1;
    }
    // 8 barrier-free ballots + per-wave prefixes
    int pfx[8];
    const unsigned long long lmask = (1ull << lane) - 1ull;
    #pragma unroll
    for (int c = 0; c < 8; ++c) {
        unsigned long long m = __ballot(nsrc[c] >= 0);
        pfx[c] = __popcll(m & lmask);
        if (lane == 0) cw[c * 4 + wave] = __popcll(m);
    }
    __syncthreads();
    if (t == 0) {
        int a = 0;
        #pragma unroll
        for (int i = 0; i < 32; ++i) { int v = cw[i]; cw[i] = a; a += v; }
        sbase = a;
        scap = (a < CMAX) ? a : CMAX;
    }
    __syncthreads();
    #pragma unroll
    for (int c = 0; c < 8; ++c) {
        int n = sb * 2048 + c * 256 + t;
        bool valid = (nsrc[c] >= 0);
        int off = cw[c * 4 + wave] + pfx[c];
        bool kept = valid && (off < CMAX);
        if (kept) plds[off] = make_int2(n, nsrc[c]);
        if (n < N) posk[n] = kept ? (unsigned char)off : (unsigned char)255;
    }
    const int cnt0 = scap;                     // valid after 2nd barrier above
    if (cnt0 == 0) return;

    bf16x8 bfr[2][4];
    #pragma unroll
    for (int nf = 0; nf < 2; ++nf)
        #pragma unroll
        for (int ks = 0; ks < 4; ++ks)
            bfr[nf][ks] = *reinterpret_cast<const bf16x8*>(
                Wp + ((size_t)((k * 4 + ks) * 8 + wave * 2 + nf) * 64 + lane) * 8);

    // ---- (b) LDS-staged gather GEMM, per 64-row tile ----
    for (int t0 = 0; t0 < cnt0; t0 += 64) {
        __syncthreads();                       // plds ready (1st iter) / Asub reuse
        #pragma unroll
        for (int j = 0; j < 4; ++j) {
            int slot = t + 256 * j;
            int row = slot >> 4, cg = slot & 15;
            int srow = t0 + row;
            bf16x8 v = {0,0,0,0,0,0,0,0};
            if (srow < cnt0) {
                int src = plds[srow].y;
                const float* fr = feats + (size_t)src * CIN + cg * 8;
                float4 x = *reinterpret_cast<const float4*>(fr);
                float4 y = *reinterpret_cast<const float4*>(fr + 4);
                v = bf16x8{ f2bf(x.x), f2bf(x.y), f2bf(x.z), f2bf(x.w),
                            f2bf(y.x), f2bf(y.y), f2bf(y.z), f2bf(y.w) };
            }
            int sw = cg ^ (row & 7);
            *reinterpret_cast<bf16x8*>(&Asub[row * 128 + sw * 8]) = v;
        }
        __syncthreads();

        f32x4 zero = {0.f, 0.f, 0.f, 0.f};
        f32x4 acc[4][2];
        #pragma unroll
        for (int mf = 0; mf < 4; ++mf) { acc[mf][0] = zero; acc[mf][1] = zero; }

        #pragma unroll
        for (int ks = 0; ks < 4; ++ks)
            #pragma unroll
            for (int mf = 0; mf < 4; ++mf) {
                int row = mf * 16 + lrow;
                int sw = (ks * 4 + lhi) ^ (lrow & 7);
                bf16x8 a = *reinterpret_cast<const bf16x8*>(&Asub[row * 128 + sw * 8]);
                acc[mf][0] = __builtin_amdgcn_mfma_f32_16x16x32_bf16(a, bfr[0][ks], acc[mf][0], 0, 0, 0);
                acc[mf][1] = __builtin_amdgcn_mfma_f32_16x16x32_bf16(a, bfr[1][ks], acc[mf][1], 0, 0, 0);
            }

        #pragma unroll
        for (int mf = 0; mf < 4; ++mf)
            #pragma unroll
            for (int j = 0; j < 4; ++j) {
                int slot = t0 + mf * 16 + lhi * 4 + j;
                if (slot >= cnt0) continue;
                short* dst = partial + ((size_t)b * CAP + slot) * COUT + wave * 32 + lrow;
                dst[0]  = f2bf(acc[mf][0][j]);
                dst[16] = f2bf(acc[mf][1][j]);
            }
    }
}

// ============================================================================
// K3 scatter_add, per 64-row tile:
//  (a) wave-parallel list build from uint8 pos (prefetched coalesced loads,
//      barrier-free ballots, t0 scan) -> k-major entry list;
//  (d) cooperative Pbuf staging (16 thr x 16B per entry row, vectorized);
//  (e) 4 threads per out row scan the entry list (execz skip for non-matching
//      waves); k-major order -> deterministic;
//  (f) rows with >=1 entry do one read-add-write of out.
// ============================================================================
__global__ __launch_bounds__(256) void scatter_add(
    const unsigned char* __restrict__ pos, const short* __restrict__ partial,
    float* __restrict__ out, int N, int nsb)
{
    __shared__ short Pbuf[EMAX][136];
    __shared__ short erowL[EMAX];
    __shared__ int   eidxL[EMAX];
    __shared__ int   kcnt[KK], koff[KK];
    __shared__ int   eTotS;

    const int tile0 = blockIdx.x * 64;
    const int sbk = tile0 >> 11;               // superblock of this tile
    const int t = threadIdx.x;
    const int wave = t >> 6, lane = t & 63;

    // ---- (a) list build: prefetch, ballot, scan, scatter ----
    int pv[7];
    #pragma unroll
    for (int rd = 0; rd < 7; ++rd) {
        int k = rd * 4 + wave;
        pv[rd] = 255;
        if (k < KK && k != 13 && tile0 + lane < N)
            pv[rd] = (int)pos[(size_t)k * N + tile0 + lane];
    }
    int mypfx[7];
    const unsigned long long lmask = (1ull << lane) - 1ull;
    #pragma unroll
    for (int rd = 0; rd < 7; ++rd) {
        int k = rd * 4 + wave;
        unsigned long long m = __ballot(pv[rd] != 255);
        mypfx[rd] = __popcll(m & lmask);
        if (k < KK && lane == 0) kcnt[k] = __popcll(m);
    }
    __syncthreads();
    if (t == 0) {
        int a = 0;
        for (int k = 0; k < KK; ++k) { koff[k] = a; a += kcnt[k]; }
        eTotS = (a < EMAX) ? a : EMAX;
    }
    __syncthreads();
    #pragma unroll
    for (int rd = 0; rd < 7; ++rd) {
        int k = rd * 4 + wave;
        if (k < KK && pv[rd] != 255) {
            int s = koff[k] + mypfx[rd];
            if (s < EMAX) {
                erowL[s] = (short)lane;
                eidxL[s] = ((k * nsb + sbk) * CAP) + pv[rd];
            }
        }
    }
    __syncthreads();
    const int eTot = eTotS;
    if (eTot == 0) return;

    // ---- (d) cooperative Pbuf staging ----
    for (int e = t >> 4; e < eTot; e += 16) {
        int sub = t & 15;
        *reinterpret_cast<bf16x8*>(&Pbuf[e][sub * 8]) =
            *reinterpret_cast<const bf16x8*>(partial + (size_t)eidxL[e] * COUT + sub * 8);
    }
    __syncthreads();

    // ---- (e) per-row predicated scan, register accumulate ----
    const int r = t >> 2, q = t & 3;           // 4 threads/row, 32 cols each
    float acc[32];
    #pragma unroll
    for (int i = 0; i < 32; ++i) acc[i] = 0.f;
    bool any = false;

    #pragma unroll 1
    for (int e = 0; e < eTot; ++e) {
        if ((int)erowL[e] != r) continue;      // execz skip
        any = true;
        #pragma unroll
        for (int v8 = 0; v8 < 4; ++v8) {
            bf16x8 p = *reinterpret_cast<const bf16x8*>(&Pbuf[e][q * 32 + v8 * 8]);
            #pragma unroll
            for (int j = 0; j < 8; ++j) acc[v8 * 8 + j] += bf2f(p[j]);
        }
    }

    // ---- (f) RMW touched out rows ----
    if (any && tile0 + r < N) {
        float* dst = out + (size_t)(tile0 + r) * COUT + q * 32;
        #pragma unroll
        for (int v4 = 0; v4 < 8; ++v4) {
            float4 o = *reinterpret_cast<float4*>(dst + v4 * 4);
            o.x += acc[v4 * 4 + 0]; o.y += acc[v4 * 4 + 1];
            o.z += acc[v4 * 4 + 2]; o.w += acc[v4 * 4 + 3];
            *reinterpret_cast<float4*>(dst + v4 * 4) = o;
        }
    }
}

// ============================================================================
// Fallback (ws too small): one block per voxel, fp32.
// ============================================================================
__global__ __launch_bounds__(128) void naive_spconv(
    const float* __restrict__ feats, const float* __restrict__ Wbase,
    const int* __restrict__ nbr, float* __restrict__ out, int N)
{
    int n  = blockIdx.x;
    int co = threadIdx.x;
    __shared__ float frow[CIN];
    float acc = 0.f;
    for (int k = 0; k < KK; ++k) {
        int src = nbr[(size_t)k * N + n];
        if (src < 0) continue;
        __syncthreads();
        frow[co] = feats[(size_t)src * CIN + co];
        __syncthreads();
        const float* Wk = Wbase + (size_t)k * CIN * COUT;
        #pragma unroll 8
        for (int ci = 0; ci < CIN; ++ci)
            acc = fmaf(frow[ci], Wk[ci * COUT + co], acc);
    }
    out[(size_t)n * COUT + co] = acc;
}

extern "C" void kernel_launch(void* const* d_in, const int* in_sizes, int n_in,
                              void* d_out, int out_size, void* d_ws, size_t ws_size,
                              hipStream_t stream) {
    const float* feats = (const float*)d_in[0];
    const float* Wb    = (const float*)d_in[1];
    const int*   nbr   = (const int*)d_in[2];
    float* out = (float*)d_out;
    const int N = in_sizes[0] / CIN;
    const int nsb = (N + 2047) >> 11;            // 2048-row superblocks
    const int nbk = KK * nsb;                    // buckets
    const int ctiles = (N + 63) / 64;

    // ws: Wp bf16 27*16384 | pos u8 27*N | partial bf16 nbk*CAP*128
    size_t off_wp   = 0;
    size_t off_pos  = ((size_t)PACK_UNITS * 8 * 2 + 255) & ~(size_t)255;
    size_t off_part = (off_pos + (size_t)KK * N + 255) & ~(size_t)255;
    size_t need = off_part + (size_t)nbk * CAP * COUT * 2;

    if (ws_size >= need) {
        short*         wp   = (short*)((char*)d_ws + off_wp);
        unsigned char* pos  = (unsigned char*)((char*)d_ws + off_pos);
        short*         part = (short*)((char*)d_ws + off_part);

        pack_W<<<PACKB, 256, 0, stream>>>(Wb, wp);
        fused_gemm<<<nbk + ctiles, 256, 0, stream>>>(wp, nbr, feats, N, nsb, nbk,
                                                     pos, part, out);
        scatter_add<<<ctiles, 256, 0, stream>>>(pos, part, out, N, nsb);
    } else {
        naive_spconv<<<N, 128, 0, stream>>>(feats, Wb, nbr, out, N);
    }
}